// Round 7
// baseline (280.981 us; speedup 1.0000x reference)
//
#include <hip/hip_runtime.h>
#include <cstdint>
#include <cstddef>

#define B_   2
#define N_   6
#define FD_  128
#define DIM_ 128
#define H_   64
#define W_   176
#define P_   (H_*W_)      // 11264
#define IMGW 704.0
#define IMGH 256.0

struct __align__(16) Samp { float wx, wy; int o00, o01; int o10, o11; int valid, pad; };

typedef __attribute__((ext_vector_type(8))) short short8;
typedef __attribute__((ext_vector_type(4))) float f32x4;

__device__ __forceinline__ float wave_sum(float v) {
#pragma unroll
  for (int off = 32; off > 0; off >>= 1) v += __shfl_xor(v, off, 64);
  return v;
}

__device__ __forceinline__ unsigned short f2bf(float f) {
  unsigned int u = __float_as_uint(f);
  unsigned int r = (u + 0x7fffu + ((u >> 16) & 1u)) >> 16;
  return (unsigned short)r;
}
__device__ __forceinline__ float bf2f(unsigned short s) {
  return __uint_as_float(((unsigned int)s) << 16);
}

// ---------------- Kernel A: fp64 homography -> sample descriptors; BN fold; MLP weight pre-swizzle ----------------
// blocks 0..11: uv/homography work. blocks 12..43: wprep (8192 threads = 128 frags x 64 lanes).
__global__ __launch_bounds__(256) void prep_kernel(const float* __restrict__ I_src, const float* __restrict__ I_tar_inv,
                           const float* __restrict__ E, const float* __restrict__ dis,
                           const float* __restrict__ nrm,
                           const float* __restrict__ bn_g, const float* __restrict__ bn_b,
                           const float* __restrict__ bn_m, const float* __restrict__ bn_v,
                           const float* __restrict__ w1, const float* __restrict__ w2,
                           Samp* __restrict__ samp, float* __restrict__ bns, float* __restrict__ bnb,
                           short* __restrict__ w1h, short* __restrict__ w1l,
                           short* __restrict__ w2h, short* __restrict__ w2l) {
  int blk = blockIdx.x;
  if (blk >= B_ * N_) {
    int tid = (blk - B_ * N_) * 256 + threadIdx.x;   // 0..8191
    int f = tid >> 6, l = tid & 63;
    if (f < 64) {
      int nt = f >> 2, ks = f & 3;
      int n = nt * 16 + (l & 15);
      int kb = ks * 32 + (l >> 4) * 8;
#pragma unroll
      for (int j = 0; j < 8; ++j) {
        float v = w1[(size_t)(kb + j) * 256 + n];
        unsigned short h = f2bf(v);
        w1h[((size_t)f * 64 + l) * 8 + j] = (short)h;
        w1l[((size_t)f * 64 + l) * 8 + j] = (short)f2bf(v - bf2f(h));
      }
    } else {
      int g = f - 64;
      int nt = g >> 3, ks = g & 7;
      int n = nt * 16 + (l & 15);
      int kb = ks * 32 + (l >> 4) * 8;
#pragma unroll
      for (int j = 0; j < 8; ++j) {
        float v = w2[(size_t)(kb + j) * 128 + n];
        unsigned short h = f2bf(v);
        w2h[((size_t)g * 64 + l) * 8 + j] = (short)h;
        w2l[((size_t)g * 64 + l) * 8 + j] = (short)f2bf(v - bf2f(h));
      }
    }
    return;
  }
  int bn = blk;                   // 0..11
  int bb = bn / N_;
  if (bn == 0 && threadIdx.x < FD_) {
    int t = threadIdx.x;
    float inv = 1.0f / sqrtf(bn_v[t] + 1e-5f);
    float sc = bn_g[t] * inv;
    bns[t] = sc;
    bnb[t] = bn_b[t] - bn_m[t] * sc;
  }
  const float* Ep = E + bn * 16;
  double R[9], T[3];
#pragma unroll
  for (int i = 0; i < 3; ++i) {
#pragma unroll
    for (int j = 0; j < 3; ++j) R[i*3+j] = (double)Ep[i*4+j];
    T[i] = (double)Ep[i*4+3];
  }
  double dd = (double)dis[bb];
  double M[9];
#pragma unroll
  for (int i = 0; i < 3; ++i)
#pragma unroll
    for (int j = 0; j < 3; ++j)
      M[i*3+j] = R[i*3+j] - T[i] * (double)nrm[bb*3+j] / dd;
  const float* Is = I_src + bn * 9;
  double A[9];
#pragma unroll
  for (int i = 0; i < 3; ++i)
#pragma unroll
    for (int j = 0; j < 3; ++j)
      A[i*3+j] = (double)Is[i*3+0]*M[0+j] + (double)Is[i*3+1]*M[3+j] + (double)Is[i*3+2]*M[6+j];
  const float* It = I_tar_inv + bb * 9;
  double Hm[9];
#pragma unroll
  for (int i = 0; i < 3; ++i)
#pragma unroll
    for (int j = 0; j < 3; ++j)
      Hm[i*3+j] = A[i*3+0]*(double)It[0+j] + A[i*3+1]*(double)It[3+j] + A[i*3+2]*(double)It[6+j];

  const double dx = 1.0 / (double)(W_ - 1);
  const double dy = 1.0 / (double)(H_ - 1);
  for (int p = threadIdx.x; p < P_; p += 256) {
    int ii = p / W_;
    int jj = p - ii * W_;
    double xs = (jj == W_ - 1) ? 1.0 : (double)jj * dx;   // np.linspace exact endpoint
    double ys = (ii == H_ - 1) ? 1.0 : (double)ii * dy;
    double px = xs * IMGW;
    double py = ys * IMGH;
    double hx = Hm[0]*px + Hm[1]*py + Hm[2];
    double hy = Hm[3]*px + Hm[4]*py + Hm[5];
    double hz = Hm[6]*px + Hm[7]*py + Hm[8];
    double u = ((hx / hz) / IMGW) * (double)W_;
    double v = ((hy / hz) / IMGH) * (double)H_;
    double x0 = floor(u), y0 = floor(v);
    bool valid = (u >= 0.0) && (u <= (double)(W_ - 1)) && (v >= 0.0) && (v <= (double)(H_ - 1));
    int x0i = min(max((int)x0, 0), W_ - 1);
    int x1i = min(x0i + 1, W_ - 1);
    int y0i = min(max((int)y0, 0), H_ - 1);
    int y1i = min(y0i + 1, H_ - 1);
    Samp s;
    s.wx = (float)(u - x0);
    s.wy = (float)(v - y0);
    s.o00 = (y0i * W_ + x0i) * DIM_;
    s.o01 = (y0i * W_ + x1i) * DIM_;
    s.o10 = (y1i * W_ + x0i) * DIM_;
    s.o11 = (y1i * W_ + x1i) * DIM_;
    s.valid = valid ? 1 : 0;
    s.pad = 0;
    samp[(size_t)bn * P_ + p] = s;
  }
}

// ---------------- Kernel B: BN+ReLU+1x1 conv as bf16 MFMA (hi/lo split X) -> val_t[bn][p][o] ----------------
__global__ __launch_bounds__(256) void conv_kernel(const float* __restrict__ feature,
    const float* __restrict__ conv_w, const float* __restrict__ bns_g, const float* __restrict__ bnb_g,
    float* __restrict__ val_t) {
  __shared__ __align__(16) short w_lds[128 * 136];  // 34816 B
  __shared__ __align__(16) short xhi[128 * 66];     // 16896 B
  __shared__ __align__(16) short xlo[128 * 66];     // 16896 B
  __shared__ float bns_s[FD_], bnb_s[FD_];
  int t = threadIdx.x;

#pragma unroll
  for (int k = 0; k < 16; ++k) {
    int f4 = t + 256 * k;
    int o  = f4 >> 5;
    int c4 = (f4 & 31) * 4;
    float4 w = *(const float4*)(conv_w + (size_t)f4 * 4);
    short* dst = &w_lds[o * 136 + c4];
    dst[0] = (short)f2bf(w.x); dst[1] = (short)f2bf(w.y);
    dst[2] = (short)f2bf(w.z); dst[3] = (short)f2bf(w.w);
  }
  if (t < FD_) { bns_s[t] = bns_g[t]; bnb_s[t] = bnb_g[t]; }
  __syncthreads();

  int bn = blockIdx.y;
  int p0 = blockIdx.x * 64;
  const float* fb = feature + (size_t)bn * FD_ * P_ + p0;

#pragma unroll
  for (int k = 0; k < 8; ++k) {
    int f4 = t + 256 * k;
    int c  = f4 >> 4;
    int pq = (f4 & 15) * 4;
    float4 x = *(const float4*)(fb + (size_t)c * P_ + pq);
    float s = bns_s[c], o = bnb_s[c];
    float v0 = fmaxf(x.x * s + o, 0.f);
    float v1 = fmaxf(x.y * s + o, 0.f);
    float v2 = fmaxf(x.z * s + o, 0.f);
    float v3 = fmaxf(x.w * s + o, 0.f);
    unsigned short h0 = f2bf(v0), h1 = f2bf(v1), h2 = f2bf(v2), h3 = f2bf(v3);
    unsigned short l0 = f2bf(v0 - bf2f(h0)), l1 = f2bf(v1 - bf2f(h1));
    unsigned short l2 = f2bf(v2 - bf2f(h2)), l3 = f2bf(v3 - bf2f(h3));
    short* dh = &xhi[c * 66 + pq];
    short* dl = &xlo[c * 66 + pq];
    dh[0] = (short)h0; dh[1] = (short)h1; dh[2] = (short)h2; dh[3] = (short)h3;
    dl[0] = (short)l0; dl[1] = (short)l1; dl[2] = (short)l2; dl[3] = (short)l3;
  }
  __syncthreads();

  int lane = t & 63, wv = t >> 6;
  int m = lane & 15, quad = lane >> 4;
  int pw = wv * 16;

  short8 Ah[4], Al[4];
#pragma unroll
  for (int ks = 0; ks < 4; ++ks) {
#pragma unroll
    for (int j = 0; j < 8; ++j) {
      int c = ks * 32 + quad * 8 + j;
      Ah[ks][j] = xhi[c * 66 + pw + m];
      Al[ks][j] = xlo[c * 66 + pw + m];
    }
  }

  f32x4 acc[8];
#pragma unroll
  for (int ot = 0; ot < 8; ++ot) {
    f32x4 a = {0.f, 0.f, 0.f, 0.f};
#pragma unroll
    for (int ks = 0; ks < 4; ++ks) {
      short8 Bv = *(const short8*)&w_lds[(ot * 16 + m) * 136 + ks * 32 + quad * 8];
      a = __builtin_amdgcn_mfma_f32_16x16x32_bf16(Ah[ks], Bv, a, 0, 0, 0);
      a = __builtin_amdgcn_mfma_f32_16x16x32_bf16(Al[ks], Bv, a, 0, 0, 0);
    }
    acc[ot] = a;
  }

  float* vb = val_t + ((size_t)bn * P_ + p0 + pw + quad * 4) * DIM_ + m;
#pragma unroll
  for (int ot = 0; ot < 8; ++ot)
#pragma unroll
    for (int r = 0; r < 4; ++r)
      vb[(size_t)r * DIM_ + ot * 16] = acc[ot][r];
}

// ---------------- Kernel C: warp-per-point bilinear attention + LN1 ----------------
__global__ __launch_bounds__(256) void attn_kernel(const float* __restrict__ val_t,
    const Samp* __restrict__ samp,
    const float* __restrict__ ln1g, const float* __restrict__ ln1b,
    float* __restrict__ zln) {
  int lane = threadIdx.x & 63;
  int wv = threadIdx.x >> 6;
  int pt = blockIdx.x * 4 + wv;
  if (pt >= B_ * P_) return;
  int bb = pt / P_;
  int p = pt - bb * P_;
  int d0 = lane << 1;

  float2 q = *(const float2*)(val_t + ((size_t)(bb * N_) * P_ + p) * DIM_ + d0);
  float qss = wave_sum(q.x * q.x + q.y * q.y);
  float qinv = 1.0f / fmaxf(sqrtf(qss), 1e-12f);
  float qn0 = q.x * qinv, qn1 = q.y * qinv;

  float dots[N_], vs0[N_], vs1[N_];
#pragma unroll
  for (int n = 0; n < N_; ++n) {
    Samp s = samp[(size_t)(bb * N_ + n) * P_ + p];
    const float* base = val_t + (size_t)(bb * N_ + n) * P_ * DIM_ + d0;
    float2 g00 = *(const float2*)(base + s.o00);
    float2 g01 = *(const float2*)(base + s.o01);
    float2 g10 = *(const float2*)(base + s.o10);
    float2 g11 = *(const float2*)(base + s.o11);
    float wx = s.wx, wy = s.wy;
    float w00 = (1.0f - wx) * (1.0f - wy), w01 = wx * (1.0f - wy);
    float w10 = (1.0f - wx) * wy,          w11 = wx * wy;
    float v0 = g00.x*w00 + g01.x*w01 + g10.x*w10 + g11.x*w11;
    float v1 = g00.y*w00 + g01.y*w01 + g10.y*w10 + g11.y*w11;
    float ss = wave_sum(v0 * v0 + v1 * v1);
    float kinv = 1.0f / fmaxf(sqrtf(ss), 1e-12f);
    float dt = wave_sum(qn0 * (v0 * kinv) + qn1 * (v1 * kinv));
    dots[n] = s.valid ? dt : 0.0f;
    vs0[n] = v0; vs1[n] = v1;
  }
  float mx = dots[0];
#pragma unroll
  for (int n = 1; n < N_; ++n) mx = fmaxf(mx, dots[n]);
  float es[N_], den = 0.f;
#pragma unroll
  for (int n = 0; n < N_; ++n) { es[n] = expf(dots[n] - mx); den += es[n]; }
  float dinv = 1.0f / den;
  float z0 = q.x, z1 = q.y;
#pragma unroll
  for (int n = 0; n < N_; ++n) { float a = es[n] * dinv; z0 += a * vs0[n]; z1 += a * vs1[n]; }
  float mean = wave_sum(z0 + z1) * (1.0f / DIM_);
  float c0 = z0 - mean, c1 = z1 - mean;
  float var = wave_sum(c0 * c0 + c1 * c1) * (1.0f / DIM_);
  float rstd = rsqrtf(var + 1e-5f);
  float o0 = c0 * rstd * ln1g[d0]     + ln1b[d0];
  float o1 = c1 * rstd * ln1g[d0 + 1] + ln1b[d0 + 1];
  *(float2*)(zln + (size_t)pt * DIM_ + d0) = make_float2(o0, o1);
}

// ---------------- Kernel D: MLP via bf16 MFMA (3-term hi/lo), split-N halves, 34.8 KB LDS -> 4 blocks/CU ----------------
// Round-6 write-once short-array style; cross-half hdn reuse is barrier-separated (__syncthreads between
// GEMM2 reads of half k and GEMM1 writes of half k+1). Per-pixel hdn row = 136 shorts (272 B) keeps
// every short8 LDS access 16-B aligned. Phases: zl (33.8 KB) -> hdn (34.8 KB) -> zo (34.8 KB).
__global__ __launch_bounds__(256, 4) void mlp_kernel(const float* __restrict__ zln,
    const short* __restrict__ w1h, const short* __restrict__ w1l,
    const short* __restrict__ w2h, const short* __restrict__ w2l,
    const float* __restrict__ b1, const float* __restrict__ b2,
    const float* __restrict__ ln2g, const float* __restrict__ ln2b,
    float* __restrict__ out) {
  __shared__ __align__(16) char smem[34816];
  int t = threadIdx.x;
  int row0 = blockIdx.x * 64;

  // ---- phase 1: zl tile (64 x 128, stride 132) ----
  float* zl = (float*)smem;
#pragma unroll
  for (int k = 0; k < 8; ++k) {
    int idx = t + 256 * k;        // 0..2047 float4s
    int r = idx >> 5, c4 = (idx & 31) * 4;
    *(float4*)&zl[r * 132 + c4] = *(const float4*)(zln + (size_t)(row0 + r) * DIM_ + c4);
  }
  __syncthreads();

  int lane = t & 63, wv = t >> 6, m = lane & 15, quad = lane >> 4;
  int pw = wv * 16;

  // A1 frags (hi/lo) from zl
  short8 A1h[4], A1l[4];
#pragma unroll
  for (int ks = 0; ks < 4; ++ks) {
    const float* zr = &zl[(pw + m) * 132 + ks * 32 + quad * 8];
#pragma unroll
    for (int j = 0; j < 8; ++j) {
      float v = zr[j];
      unsigned short h = f2bf(v);
      A1h[ks][j] = (short)h;
      A1l[ks][j] = (short)f2bf(v - bf2f(h));
    }
  }
  // residual to registers (C-layout positions this lane will own)
  float res[8][4];
#pragma unroll
  for (int nt = 0; nt < 8; ++nt)
#pragma unroll
    for (int r = 0; r < 4; ++r)
      res[nt][r] = zl[(pw + quad * 4 + r) * 132 + nt * 16 + m];

  float b1v[16];
#pragma unroll
  for (int nt = 0; nt < 16; ++nt) b1v[nt] = b1[nt * 16 + m];
  float b2v[8], g2v[8], be2v[8];
#pragma unroll
  for (int nt = 0; nt < 8; ++nt) {
    b2v[nt] = b2[nt * 16 + m];
    g2v[nt] = ln2g[nt * 16 + m];
    be2v[nt] = ln2b[nt * 16 + m];
  }
  __syncthreads();   // zl dead; smem becomes hdn

  // ---- phase 2: hdn halves (per-wave 16 x 136 shorts; hi at [0,17408), lo at [17408,34816)) ----
  short* hh = (short*)smem + wv * (16 * 136);
  short* hl = (short*)(smem + 17408) + wv * (16 * 136);

  f32x4 acc2[8];
#pragma unroll
  for (int nt = 0; nt < 8; ++nt) acc2[nt] = (f32x4){0.f, 0.f, 0.f, 0.f};

#pragma unroll
  for (int half = 0; half < 2; ++half) {
    if (half) __syncthreads();   // protect previous half's reads from this half's writes (WAR)
    // GEMM1 for hidden tiles nt = half*8 .. half*8+7
#pragma unroll
    for (int ntl = 0; ntl < 8; ++ntl) {
      int nt = half * 8 + ntl;
      f32x4 a = {0.f, 0.f, 0.f, 0.f};
#pragma unroll
      for (int ks = 0; ks < 4; ++ks) {
        short8 Bh = *(const short8*)(w1h + ((size_t)(nt * 4 + ks) * 64 + lane) * 8);
        short8 Bl = *(const short8*)(w1l + ((size_t)(nt * 4 + ks) * 64 + lane) * 8);
        a = __builtin_amdgcn_mfma_f32_16x16x32_bf16(A1h[ks], Bh, a, 0, 0, 0);
        a = __builtin_amdgcn_mfma_f32_16x16x32_bf16(A1l[ks], Bh, a, 0, 0, 0);
        a = __builtin_amdgcn_mfma_f32_16x16x32_bf16(A1h[ks], Bl, a, 0, 0, 0);
      }
#pragma unroll
      for (int r = 0; r < 4; ++r) {
        float hv = a[r] + b1v[nt];
        float g = 0.5f * hv * (1.0f + erff(hv * 0.70710678118654752f));
        unsigned short gh = f2bf(g);
        int addr = (quad * 4 + r) * 136 + ntl * 16 + m;
        hh[addr] = (short)gh;
        hl[addr] = (short)f2bf(g - bf2f(gh));
      }
    }
    __syncthreads();   // writes ordered before reads
    // GEMM2 partial over this half's k-range
#pragma unroll
    for (int ks2 = 0; ks2 < 4; ++ks2) {
      short8 A2h = *(const short8*)&hh[m * 136 + ks2 * 32 + quad * 8];
      short8 A2l = *(const short8*)&hl[m * 136 + ks2 * 32 + quad * 8];
#pragma unroll
      for (int nt = 0; nt < 8; ++nt) {
        int g = nt * 8 + half * 4 + ks2;
        short8 Bh = *(const short8*)(w2h + ((size_t)g * 64 + lane) * 8);
        short8 Bl = *(const short8*)(w2l + ((size_t)g * 64 + lane) * 8);
        acc2[nt] = __builtin_amdgcn_mfma_f32_16x16x32_bf16(A2h, Bh, acc2[nt], 0, 0, 0);
        acc2[nt] = __builtin_amdgcn_mfma_f32_16x16x32_bf16(A2l, Bh, acc2[nt], 0, 0, 0);
        acc2[nt] = __builtin_amdgcn_mfma_f32_16x16x32_bf16(A2h, Bl, acc2[nt], 0, 0, 0);
      }
    }
  }

  // bias + residual + LN2 (per-pixel stats via m-group shuffles)
  float z2[8][4], mean[4], rstd[4];
#pragma unroll
  for (int r = 0; r < 4; ++r) {
    float s = 0.f;
#pragma unroll
    for (int nt = 0; nt < 8; ++nt) {
      float v = acc2[nt][r] + b2v[nt] + res[nt][r];
      z2[nt][r] = v;
      s += v;
    }
    s += __shfl_xor(s, 1, 64); s += __shfl_xor(s, 2, 64);
    s += __shfl_xor(s, 4, 64); s += __shfl_xor(s, 8, 64);
    mean[r] = s * (1.0f / 128.0f);
    float vv = 0.f;
#pragma unroll
    for (int nt = 0; nt < 8; ++nt) { float d = z2[nt][r] - mean[r]; vv += d * d; }
    vv += __shfl_xor(vv, 1, 64); vv += __shfl_xor(vv, 2, 64);
    vv += __shfl_xor(vv, 4, 64); vv += __shfl_xor(vv, 8, 64);
    rstd[r] = rsqrtf(vv * (1.0f / 128.0f) + 1e-5f);
  }

  __syncthreads();   // all hdn reads done before zo overlay
  // ---- phase 3: zo transpose buffer (128 x 68 floats) ----
  float* zo = (float*)smem;
#pragma unroll
  for (int nt = 0; nt < 8; ++nt)
#pragma unroll
    for (int r = 0; r < 4; ++r) {
      float v = (z2[nt][r] - mean[r]) * rstd[r] * g2v[nt] + be2v[nt];
      zo[(nt * 16 + m) * 68 + pw + quad * 4 + r] = v;
    }
  __syncthreads();

  // coalesced transposed store: out[b][d][p]
  int bb2 = row0 / P_;
  int p0 = row0 - bb2 * P_;
#pragma unroll
  for (int it = 0; it < 8; ++it) {
    int d = it * 16 + (t >> 4);
    int pq = (t & 15) * 4;
    float4 v4 = *(float4*)&zo[d * 68 + pq];
    *(float4*)(out + (size_t)bb2 * DIM_ * P_ + (size_t)d * P_ + p0 + pq) = v4;
  }
}

extern "C" void kernel_launch(void* const* d_in, const int* in_sizes, int n_in,
                              void* d_out, int out_size, void* d_ws, size_t ws_size,
                              hipStream_t stream) {
  const float* feature = (const float*)d_in[0];
  const float* I_src   = (const float*)d_in[1];
  const float* I_tar   = (const float*)d_in[2];
  const float* E       = (const float*)d_in[3];
  const float* dis     = (const float*)d_in[4];
  const float* nrm     = (const float*)d_in[5];
  const float* conv_w  = (const float*)d_in[6];
  const float* bn_g    = (const float*)d_in[7];
  const float* bn_b    = (const float*)d_in[8];
  const float* bn_m    = (const float*)d_in[9];
  const float* bn_v    = (const float*)d_in[10];
  const float* ln1g    = (const float*)d_in[11];
  const float* ln1b    = (const float*)d_in[12];
  const float* ln2g    = (const float*)d_in[13];
  const float* ln2b    = (const float*)d_in[14];
  const float* w1      = (const float*)d_in[15];
  const float* b1      = (const float*)d_in[16];
  const float* w2      = (const float*)d_in[17];
  const float* b2      = (const float*)d_in[18];
  float* out = (float*)d_out;

  float* wsf   = (float*)d_ws;
  float* bns   = wsf;                 // 128
  float* bnb   = wsf + 128;           // 128
  float* val_t = wsf + 256;           // B*N*P*DIM floats
  float* zln   = val_t + (size_t)B_ * N_ * P_ * DIM_;   // B*P*DIM floats
  Samp*  samp  = (Samp*)(zln + (size_t)B_ * P_ * DIM_); // 12*P structs (32B each)
  short* w1h   = (short*)(samp + (size_t)B_ * N_ * P_); // 32768 shorts each
  short* w1l   = w1h + 32768;
  short* w2h   = w1l + 32768;
  short* w2l   = w2h + 32768;

  hipLaunchKernelGGL(prep_kernel, dim3(B_ * N_ + 32), dim3(256), 0, stream,
                     I_src, I_tar, E, dis, nrm, bn_g, bn_b, bn_m, bn_v, w1, w2,
                     samp, bns, bnb, w1h, w1l, w2h, w2l);
  hipLaunchKernelGGL(conv_kernel, dim3(P_ / 64, B_ * N_), dim3(256), 0, stream,
                     feature, conv_w, bns, bnb, val_t);
  hipLaunchKernelGGL(attn_kernel, dim3(B_ * P_ / 4), dim3(256), 0, stream,
                     val_t, samp, ln1g, ln1b, zln);
  hipLaunchKernelGGL(mlp_kernel, dim3(B_ * P_ / 64), dim3(256), 0, stream,
                     zln, w1h, w1l, w2h, w2l, b1, b2, ln2g, ln2b, out);
}

// Round 8
// 243.765 us; speedup vs baseline: 1.1527x; 1.1527x over previous
//
#include <hip/hip_runtime.h>
#include <cstdint>
#include <cstddef>

#define B_   2
#define N_   6
#define FD_  128
#define DIM_ 128
#define H_   64
#define W_   176
#define P_   (H_*W_)      // 11264
#define IMGW 704.0
#define IMGH 256.0

struct __align__(16) Samp { float wx, wy; int o00, o01; int o10, o11; int valid, pad; };

typedef __attribute__((ext_vector_type(8))) short short8;
typedef __attribute__((ext_vector_type(4))) float f32x4;

__device__ __forceinline__ float wave_sum(float v) {
#pragma unroll
  for (int off = 32; off > 0; off >>= 1) v += __shfl_xor(v, off, 64);
  return v;
}

__device__ __forceinline__ unsigned short f2bf(float f) {
  unsigned int u = __float_as_uint(f);
  unsigned int r = (u + 0x7fffu + ((u >> 16) & 1u)) >> 16;
  return (unsigned short)r;
}
__device__ __forceinline__ float bf2f(unsigned short s) {
  return __uint_as_float(((unsigned int)s) << 16);
}

// ---------------- Kernel A: fp64 homography -> sample descriptors; BN fold; MLP weight pre-swizzle ----------------
// blocks 0..11: uv/homography work. blocks 12..43: wprep (8192 threads = 128 frags x 64 lanes).
__global__ __launch_bounds__(256) void prep_kernel(const float* __restrict__ I_src, const float* __restrict__ I_tar_inv,
                           const float* __restrict__ E, const float* __restrict__ dis,
                           const float* __restrict__ nrm,
                           const float* __restrict__ bn_g, const float* __restrict__ bn_b,
                           const float* __restrict__ bn_m, const float* __restrict__ bn_v,
                           const float* __restrict__ w1, const float* __restrict__ w2,
                           Samp* __restrict__ samp, float* __restrict__ bns, float* __restrict__ bnb,
                           short* __restrict__ w1h, short* __restrict__ w1l,
                           short* __restrict__ w2h, short* __restrict__ w2l) {
  int blk = blockIdx.x;
  if (blk >= B_ * N_) {
    int tid = (blk - B_ * N_) * 256 + threadIdx.x;   // 0..8191
    int f = tid >> 6, l = tid & 63;
    if (f < 64) {
      int nt = f >> 2, ks = f & 3;
      int n = nt * 16 + (l & 15);
      int kb = ks * 32 + (l >> 4) * 8;
#pragma unroll
      for (int j = 0; j < 8; ++j) {
        float v = w1[(size_t)(kb + j) * 256 + n];
        unsigned short h = f2bf(v);
        w1h[((size_t)f * 64 + l) * 8 + j] = (short)h;
        w1l[((size_t)f * 64 + l) * 8 + j] = (short)f2bf(v - bf2f(h));
      }
    } else {
      int g = f - 64;
      int nt = g >> 3, ks = g & 7;
      int n = nt * 16 + (l & 15);
      int kb = ks * 32 + (l >> 4) * 8;
#pragma unroll
      for (int j = 0; j < 8; ++j) {
        float v = w2[(size_t)(kb + j) * 128 + n];
        unsigned short h = f2bf(v);
        w2h[((size_t)g * 64 + l) * 8 + j] = (short)h;
        w2l[((size_t)g * 64 + l) * 8 + j] = (short)f2bf(v - bf2f(h));
      }
    }
    return;
  }
  int bn = blk;                   // 0..11
  int bb = bn / N_;
  if (bn == 0 && threadIdx.x < FD_) {
    int t = threadIdx.x;
    float inv = 1.0f / sqrtf(bn_v[t] + 1e-5f);
    float sc = bn_g[t] * inv;
    bns[t] = sc;
    bnb[t] = bn_b[t] - bn_m[t] * sc;
  }
  const float* Ep = E + bn * 16;
  double R[9], T[3];
#pragma unroll
  for (int i = 0; i < 3; ++i) {
#pragma unroll
    for (int j = 0; j < 3; ++j) R[i*3+j] = (double)Ep[i*4+j];
    T[i] = (double)Ep[i*4+3];
  }
  double dd = (double)dis[bb];
  double M[9];
#pragma unroll
  for (int i = 0; i < 3; ++i)
#pragma unroll
    for (int j = 0; j < 3; ++j)
      M[i*3+j] = R[i*3+j] - T[i] * (double)nrm[bb*3+j] / dd;
  const float* Is = I_src + bn * 9;
  double A[9];
#pragma unroll
  for (int i = 0; i < 3; ++i)
#pragma unroll
    for (int j = 0; j < 3; ++j)
      A[i*3+j] = (double)Is[i*3+0]*M[0+j] + (double)Is[i*3+1]*M[3+j] + (double)Is[i*3+2]*M[6+j];
  const float* It = I_tar_inv + bb * 9;
  double Hm[9];
#pragma unroll
  for (int i = 0; i < 3; ++i)
#pragma unroll
    for (int j = 0; j < 3; ++j)
      Hm[i*3+j] = A[i*3+0]*(double)It[0+j] + A[i*3+1]*(double)It[3+j] + A[i*3+2]*(double)It[6+j];

  const double dx = 1.0 / (double)(W_ - 1);
  const double dy = 1.0 / (double)(H_ - 1);
  for (int p = threadIdx.x; p < P_; p += 256) {
    int ii = p / W_;
    int jj = p - ii * W_;
    double xs = (jj == W_ - 1) ? 1.0 : (double)jj * dx;   // np.linspace exact endpoint
    double ys = (ii == H_ - 1) ? 1.0 : (double)ii * dy;
    double px = xs * IMGW;
    double py = ys * IMGH;
    double hx = Hm[0]*px + Hm[1]*py + Hm[2];
    double hy = Hm[3]*px + Hm[4]*py + Hm[5];
    double hz = Hm[6]*px + Hm[7]*py + Hm[8];
    double u = ((hx / hz) / IMGW) * (double)W_;
    double v = ((hy / hz) / IMGH) * (double)H_;
    double x0 = floor(u), y0 = floor(v);
    bool valid = (u >= 0.0) && (u <= (double)(W_ - 1)) && (v >= 0.0) && (v <= (double)(H_ - 1));
    int x0i = min(max((int)x0, 0), W_ - 1);
    int x1i = min(x0i + 1, W_ - 1);
    int y0i = min(max((int)y0, 0), H_ - 1);
    int y1i = min(y0i + 1, H_ - 1);
    Samp s;
    s.wx = (float)(u - x0);
    s.wy = (float)(v - y0);
    s.o00 = (y0i * W_ + x0i) * DIM_;
    s.o01 = (y0i * W_ + x1i) * DIM_;
    s.o10 = (y1i * W_ + x0i) * DIM_;
    s.o11 = (y1i * W_ + x1i) * DIM_;
    s.valid = valid ? 1 : 0;
    s.pad = 0;
    samp[(size_t)bn * P_ + p] = s;
  }
}

// ---------------- Kernel B: BN+ReLU+1x1 conv as bf16 MFMA (hi/lo split X) -> val_t[bn][p][o] ----------------
__global__ __launch_bounds__(256) void conv_kernel(const float* __restrict__ feature,
    const float* __restrict__ conv_w, const float* __restrict__ bns_g, const float* __restrict__ bnb_g,
    float* __restrict__ val_t) {
  __shared__ __align__(16) short w_lds[128 * 136];  // 34816 B
  __shared__ __align__(16) short xhi[128 * 66];     // 16896 B
  __shared__ __align__(16) short xlo[128 * 66];     // 16896 B
  __shared__ float bns_s[FD_], bnb_s[FD_];
  int t = threadIdx.x;

#pragma unroll
  for (int k = 0; k < 16; ++k) {
    int f4 = t + 256 * k;
    int o  = f4 >> 5;
    int c4 = (f4 & 31) * 4;
    float4 w = *(const float4*)(conv_w + (size_t)f4 * 4);
    short* dst = &w_lds[o * 136 + c4];
    dst[0] = (short)f2bf(w.x); dst[1] = (short)f2bf(w.y);
    dst[2] = (short)f2bf(w.z); dst[3] = (short)f2bf(w.w);
  }
  if (t < FD_) { bns_s[t] = bns_g[t]; bnb_s[t] = bnb_g[t]; }
  __syncthreads();

  int bn = blockIdx.y;
  int p0 = blockIdx.x * 64;
  const float* fb = feature + (size_t)bn * FD_ * P_ + p0;

#pragma unroll
  for (int k = 0; k < 8; ++k) {
    int f4 = t + 256 * k;
    int c  = f4 >> 4;
    int pq = (f4 & 15) * 4;
    float4 x = *(const float4*)(fb + (size_t)c * P_ + pq);
    float s = bns_s[c], o = bnb_s[c];
    float v0 = fmaxf(x.x * s + o, 0.f);
    float v1 = fmaxf(x.y * s + o, 0.f);
    float v2 = fmaxf(x.z * s + o, 0.f);
    float v3 = fmaxf(x.w * s + o, 0.f);
    unsigned short h0 = f2bf(v0), h1 = f2bf(v1), h2 = f2bf(v2), h3 = f2bf(v3);
    unsigned short l0 = f2bf(v0 - bf2f(h0)), l1 = f2bf(v1 - bf2f(h1));
    unsigned short l2 = f2bf(v2 - bf2f(h2)), l3 = f2bf(v3 - bf2f(h3));
    short* dh = &xhi[c * 66 + pq];
    short* dl = &xlo[c * 66 + pq];
    dh[0] = (short)h0; dh[1] = (short)h1; dh[2] = (short)h2; dh[3] = (short)h3;
    dl[0] = (short)l0; dl[1] = (short)l1; dl[2] = (short)l2; dl[3] = (short)l3;
  }
  __syncthreads();

  int lane = t & 63, wv = t >> 6;
  int m = lane & 15, quad = lane >> 4;
  int pw = wv * 16;

  short8 Ah[4], Al[4];
#pragma unroll
  for (int ks = 0; ks < 4; ++ks) {
#pragma unroll
    for (int j = 0; j < 8; ++j) {
      int c = ks * 32 + quad * 8 + j;
      Ah[ks][j] = xhi[c * 66 + pw + m];
      Al[ks][j] = xlo[c * 66 + pw + m];
    }
  }

  f32x4 acc[8];
#pragma unroll
  for (int ot = 0; ot < 8; ++ot) {
    f32x4 a = {0.f, 0.f, 0.f, 0.f};
#pragma unroll
    for (int ks = 0; ks < 4; ++ks) {
      short8 Bv = *(const short8*)&w_lds[(ot * 16 + m) * 136 + ks * 32 + quad * 8];
      a = __builtin_amdgcn_mfma_f32_16x16x32_bf16(Ah[ks], Bv, a, 0, 0, 0);
      a = __builtin_amdgcn_mfma_f32_16x16x32_bf16(Al[ks], Bv, a, 0, 0, 0);
    }
    acc[ot] = a;
  }

  float* vb = val_t + ((size_t)bn * P_ + p0 + pw + quad * 4) * DIM_ + m;
#pragma unroll
  for (int ot = 0; ot < 8; ++ot)
#pragma unroll
    for (int r = 0; r < 4; ++r)
      vb[(size_t)r * DIM_ + ot * 16] = acc[ot][r];
}

// ---------------- Kernel C: warp-per-point bilinear attention + LN1 ----------------
__global__ __launch_bounds__(256) void attn_kernel(const float* __restrict__ val_t,
    const Samp* __restrict__ samp,
    const float* __restrict__ ln1g, const float* __restrict__ ln1b,
    float* __restrict__ zln) {
  int lane = threadIdx.x & 63;
  int wv = threadIdx.x >> 6;
  int pt = blockIdx.x * 4 + wv;
  if (pt >= B_ * P_) return;
  int bb = pt / P_;
  int p = pt - bb * P_;
  int d0 = lane << 1;

  float2 q = *(const float2*)(val_t + ((size_t)(bb * N_) * P_ + p) * DIM_ + d0);
  float qss = wave_sum(q.x * q.x + q.y * q.y);
  float qinv = 1.0f / fmaxf(sqrtf(qss), 1e-12f);
  float qn0 = q.x * qinv, qn1 = q.y * qinv;

  float dots[N_], vs0[N_], vs1[N_];
#pragma unroll
  for (int n = 0; n < N_; ++n) {
    Samp s = samp[(size_t)(bb * N_ + n) * P_ + p];
    const float* base = val_t + (size_t)(bb * N_ + n) * P_ * DIM_ + d0;
    float2 g00 = *(const float2*)(base + s.o00);
    float2 g01 = *(const float2*)(base + s.o01);
    float2 g10 = *(const float2*)(base + s.o10);
    float2 g11 = *(const float2*)(base + s.o11);
    float wx = s.wx, wy = s.wy;
    float w00 = (1.0f - wx) * (1.0f - wy), w01 = wx * (1.0f - wy);
    float w10 = (1.0f - wx) * wy,          w11 = wx * wy;
    float v0 = g00.x*w00 + g01.x*w01 + g10.x*w10 + g11.x*w11;
    float v1 = g00.y*w00 + g01.y*w01 + g10.y*w10 + g11.y*w11;
    float ss = wave_sum(v0 * v0 + v1 * v1);
    float kinv = 1.0f / fmaxf(sqrtf(ss), 1e-12f);
    float dt = wave_sum(qn0 * (v0 * kinv) + qn1 * (v1 * kinv));
    dots[n] = s.valid ? dt : 0.0f;
    vs0[n] = v0; vs1[n] = v1;
  }
  float mx = dots[0];
#pragma unroll
  for (int n = 1; n < N_; ++n) mx = fmaxf(mx, dots[n]);
  float es[N_], den = 0.f;
#pragma unroll
  for (int n = 0; n < N_; ++n) { es[n] = expf(dots[n] - mx); den += es[n]; }
  float dinv = 1.0f / den;
  float z0 = q.x, z1 = q.y;
#pragma unroll
  for (int n = 0; n < N_; ++n) { float a = es[n] * dinv; z0 += a * vs0[n]; z1 += a * vs1[n]; }
  float mean = wave_sum(z0 + z1) * (1.0f / DIM_);
  float c0 = z0 - mean, c1 = z1 - mean;
  float var = wave_sum(c0 * c0 + c1 * c1) * (1.0f / DIM_);
  float rstd = rsqrtf(var + 1e-5f);
  float o0 = c0 * rstd * ln1g[d0]     + ln1b[d0];
  float o1 = c1 * rstd * ln1g[d0 + 1] + ln1b[d0 + 1];
  *(float2*)(zln + (size_t)pt * DIM_ + d0) = make_float2(o0, o1);
}

// ---------------- Kernel D: MLP via bf16 MFMA (3-term hi/lo), split-N halves, 34.8 KB LDS ----------------
// No waves-per-EU constraint: round 7's (256,4) squeezed VGPRs to 64 and spilled 49 MB to scratch.
// Plain bounds -> ~124 VGPR (<=128 allows 4 waves/SIMD) and 34.8 KB LDS allows 4 blocks/CU.
__global__ __launch_bounds__(256) void mlp_kernel(const float* __restrict__ zln,
    const short* __restrict__ w1h, const short* __restrict__ w1l,
    const short* __restrict__ w2h, const short* __restrict__ w2l,
    const float* __restrict__ b1, const float* __restrict__ b2,
    const float* __restrict__ ln2g, const float* __restrict__ ln2b,
    float* __restrict__ out) {
  __shared__ __align__(16) char smem[34816];
  int t = threadIdx.x;
  int row0 = blockIdx.x * 64;

  // ---- phase 1: zl tile (64 x 128, stride 132) ----
  float* zl = (float*)smem;
#pragma unroll
  for (int k = 0; k < 8; ++k) {
    int idx = t + 256 * k;        // 0..2047 float4s
    int r = idx >> 5, c4 = (idx & 31) * 4;
    *(float4*)&zl[r * 132 + c4] = *(const float4*)(zln + (size_t)(row0 + r) * DIM_ + c4);
  }
  __syncthreads();

  int lane = t & 63, wv = t >> 6, m = lane & 15, quad = lane >> 4;
  int pw = wv * 16;

  // A1 frags (hi/lo) from zl
  short8 A1h[4], A1l[4];
#pragma unroll
  for (int ks = 0; ks < 4; ++ks) {
    const float* zr = &zl[(pw + m) * 132 + ks * 32 + quad * 8];
#pragma unroll
    for (int j = 0; j < 8; ++j) {
      float v = zr[j];
      unsigned short h = f2bf(v);
      A1h[ks][j] = (short)h;
      A1l[ks][j] = (short)f2bf(v - bf2f(h));
    }
  }
  // residual to registers (C-layout positions this lane will own)
  float res[8][4];
#pragma unroll
  for (int nt = 0; nt < 8; ++nt)
#pragma unroll
    for (int r = 0; r < 4; ++r)
      res[nt][r] = zl[(pw + quad * 4 + r) * 132 + nt * 16 + m];

  float b1v[16];
#pragma unroll
  for (int nt = 0; nt < 16; ++nt) b1v[nt] = b1[nt * 16 + m];
  float b2v[8], g2v[8], be2v[8];
#pragma unroll
  for (int nt = 0; nt < 8; ++nt) {
    b2v[nt] = b2[nt * 16 + m];
    g2v[nt] = ln2g[nt * 16 + m];
    be2v[nt] = ln2b[nt * 16 + m];
  }
  __syncthreads();   // zl dead; smem becomes hdn

  // ---- phase 2: hdn halves (per-wave 16 x 136 shorts; hi at [0,17408), lo at [17408,34816)) ----
  short* hh = (short*)smem + wv * (16 * 136);
  short* hl = (short*)(smem + 17408) + wv * (16 * 136);

  f32x4 acc2[8];
#pragma unroll
  for (int nt = 0; nt < 8; ++nt) acc2[nt] = (f32x4){0.f, 0.f, 0.f, 0.f};

#pragma unroll
  for (int half = 0; half < 2; ++half) {
    if (half) __syncthreads();   // protect previous half's reads from this half's writes (WAR)
    // GEMM1 for hidden tiles nt = half*8 .. half*8+7
#pragma unroll
    for (int ntl = 0; ntl < 8; ++ntl) {
      int nt = half * 8 + ntl;
      f32x4 a = {0.f, 0.f, 0.f, 0.f};
#pragma unroll
      for (int ks = 0; ks < 4; ++ks) {
        short8 Bh = *(const short8*)(w1h + ((size_t)(nt * 4 + ks) * 64 + lane) * 8);
        short8 Bl = *(const short8*)(w1l + ((size_t)(nt * 4 + ks) * 64 + lane) * 8);
        a = __builtin_amdgcn_mfma_f32_16x16x32_bf16(A1h[ks], Bh, a, 0, 0, 0);
        a = __builtin_amdgcn_mfma_f32_16x16x32_bf16(A1l[ks], Bh, a, 0, 0, 0);
        a = __builtin_amdgcn_mfma_f32_16x16x32_bf16(A1h[ks], Bl, a, 0, 0, 0);
      }
#pragma unroll
      for (int r = 0; r < 4; ++r) {
        float hv = a[r] + b1v[nt];
        float g = 0.5f * hv * (1.0f + erff(hv * 0.70710678118654752f));
        unsigned short gh = f2bf(g);
        int addr = (quad * 4 + r) * 136 + ntl * 16 + m;
        hh[addr] = (short)gh;
        hl[addr] = (short)f2bf(g - bf2f(gh));
      }
    }
    __syncthreads();   // writes ordered before reads
    // GEMM2 partial over this half's k-range
#pragma unroll
    for (int ks2 = 0; ks2 < 4; ++ks2) {
      short8 A2h = *(const short8*)&hh[m * 136 + ks2 * 32 + quad * 8];
      short8 A2l = *(const short8*)&hl[m * 136 + ks2 * 32 + quad * 8];
#pragma unroll
      for (int nt = 0; nt < 8; ++nt) {
        int g = nt * 8 + half * 4 + ks2;
        short8 Bh = *(const short8*)(w2h + ((size_t)g * 64 + lane) * 8);
        short8 Bl = *(const short8*)(w2l + ((size_t)g * 64 + lane) * 8);
        acc2[nt] = __builtin_amdgcn_mfma_f32_16x16x32_bf16(A2h, Bh, acc2[nt], 0, 0, 0);
        acc2[nt] = __builtin_amdgcn_mfma_f32_16x16x32_bf16(A2l, Bh, acc2[nt], 0, 0, 0);
        acc2[nt] = __builtin_amdgcn_mfma_f32_16x16x32_bf16(A2h, Bl, acc2[nt], 0, 0, 0);
      }
    }
  }

  // bias + residual + LN2 (per-pixel stats via m-group shuffles)
  float z2[8][4], mean[4], rstd[4];
#pragma unroll
  for (int r = 0; r < 4; ++r) {
    float s = 0.f;
#pragma unroll
    for (int nt = 0; nt < 8; ++nt) {
      float v = acc2[nt][r] + b2v[nt] + res[nt][r];
      z2[nt][r] = v;
      s += v;
    }
    s += __shfl_xor(s, 1, 64); s += __shfl_xor(s, 2, 64);
    s += __shfl_xor(s, 4, 64); s += __shfl_xor(s, 8, 64);
    mean[r] = s * (1.0f / 128.0f);
    float vv = 0.f;
#pragma unroll
    for (int nt = 0; nt < 8; ++nt) { float d = z2[nt][r] - mean[r]; vv += d * d; }
    vv += __shfl_xor(vv, 1, 64); vv += __shfl_xor(vv, 2, 64);
    vv += __shfl_xor(vv, 4, 64); vv += __shfl_xor(vv, 8, 64);
    rstd[r] = rsqrtf(vv * (1.0f / 128.0f) + 1e-5f);
  }

  __syncthreads();   // all hdn reads done before zo overlay
  // ---- phase 3: zo transpose buffer (128 x 68 floats) ----
  float* zo = (float*)smem;
#pragma unroll
  for (int nt = 0; nt < 8; ++nt)
#pragma unroll
    for (int r = 0; r < 4; ++r) {
      float v = (z2[nt][r] - mean[r]) * rstd[r] * g2v[nt] + be2v[nt];
      zo[(nt * 16 + m) * 68 + pw + quad * 4 + r] = v;
    }
  __syncthreads();

  // coalesced transposed store: out[b][d][p]
  int bb2 = row0 / P_;
  int p0 = row0 - bb2 * P_;
#pragma unroll
  for (int it = 0; it < 8; ++it) {
    int d = it * 16 + (t >> 4);
    int pq = (t & 15) * 4;
    float4 v4 = *(float4*)&zo[d * 68 + pq];
    *(float4*)(out + (size_t)bb2 * DIM_ * P_ + (size_t)d * P_ + p0 + pq) = v4;
  }
}

extern "C" void kernel_launch(void* const* d_in, const int* in_sizes, int n_in,
                              void* d_out, int out_size, void* d_ws, size_t ws_size,
                              hipStream_t stream) {
  const float* feature = (const float*)d_in[0];
  const float* I_src   = (const float*)d_in[1];
  const float* I_tar   = (const float*)d_in[2];
  const float* E       = (const float*)d_in[3];
  const float* dis     = (const float*)d_in[4];
  const float* nrm     = (const float*)d_in[5];
  const float* conv_w  = (const float*)d_in[6];
  const float* bn_g    = (const float*)d_in[7];
  const float* bn_b    = (const float*)d_in[8];
  const float* bn_m    = (const float*)d_in[9];
  const float* bn_v    = (const float*)d_in[10];
  const float* ln1g    = (const float*)d_in[11];
  const float* ln1b    = (const float*)d_in[12];
  const float* ln2g    = (const float*)d_in[13];
  const float* ln2b    = (const float*)d_in[14];
  const float* w1      = (const float*)d_in[15];
  const float* b1      = (const float*)d_in[16];
  const float* w2      = (const float*)d_in[17];
  const float* b2      = (const float*)d_in[18];
  float* out = (float*)d_out;

  float* wsf   = (float*)d_ws;
  float* bns   = wsf;                 // 128
  float* bnb   = wsf + 128;           // 128
  float* val_t = wsf + 256;           // B*N*P*DIM floats
  float* zln   = val_t + (size_t)B_ * N_ * P_ * DIM_;   // B*P*DIM floats
  Samp*  samp  = (Samp*)(zln + (size_t)B_ * P_ * DIM_); // 12*P structs (32B each)
  short* w1h   = (short*)(samp + (size_t)B_ * N_ * P_); // 32768 shorts each
  short* w1l   = w1h + 32768;
  short* w2h   = w1l + 32768;
  short* w2l   = w2h + 32768;

  hipLaunchKernelGGL(prep_kernel, dim3(B_ * N_ + 32), dim3(256), 0, stream,
                     I_src, I_tar, E, dis, nrm, bn_g, bn_b, bn_m, bn_v, w1, w2,
                     samp, bns, bnb, w1h, w1l, w2h, w2l);
  hipLaunchKernelGGL(conv_kernel, dim3(P_ / 64, B_ * N_), dim3(256), 0, stream,
                     feature, conv_w, bns, bnb, val_t);
  hipLaunchKernelGGL(attn_kernel, dim3(B_ * P_ / 4), dim3(256), 0, stream,
                     val_t, samp, ln1g, ln1b, zln);
  hipLaunchKernelGGL(mlp_kernel, dim3(B_ * P_ / 64), dim3(256), 0, stream,
                     zln, w1h, w1l, w2h, w2l, b1, b2, ln2g, ln2b, out);
}

// Round 9
// 234.307 us; speedup vs baseline: 1.1992x; 1.0404x over previous
//
#include <hip/hip_runtime.h>
#include <cstdint>
#include <cstddef>

#define B_   2
#define N_   6
#define FD_  128
#define DIM_ 128
#define H_   64
#define W_   176
#define P_   (H_*W_)      // 11264
#define IMGW 704.0
#define IMGH 256.0

struct __align__(16) Samp { float wx, wy; int o00, o01; int o10, o11; int valid, pad; };

typedef __attribute__((ext_vector_type(8))) short short8;
typedef __attribute__((ext_vector_type(4))) float f32x4;

__device__ __forceinline__ float wave_sum(float v) {
#pragma unroll
  for (int off = 32; off > 0; off >>= 1) v += __shfl_xor(v, off, 64);
  return v;
}

__device__ __forceinline__ unsigned short f2bf(float f) {
  unsigned int u = __float_as_uint(f);
  unsigned int r = (u + 0x7fffu + ((u >> 16) & 1u)) >> 16;
  return (unsigned short)r;
}
__device__ __forceinline__ float bf2f(unsigned short s) {
  return __uint_as_float(((unsigned int)s) << 16);
}

// ---------------- Kernel A: fp64 homography -> sample descriptors; BN fold; MLP weight pre-swizzle ----------------
__global__ __launch_bounds__(256) void prep_kernel(const float* __restrict__ I_src, const float* __restrict__ I_tar_inv,
                           const float* __restrict__ E, const float* __restrict__ dis,
                           const float* __restrict__ nrm,
                           const float* __restrict__ bn_g, const float* __restrict__ bn_b,
                           const float* __restrict__ bn_m, const float* __restrict__ bn_v,
                           const float* __restrict__ w1, const float* __restrict__ w2,
                           Samp* __restrict__ samp, float* __restrict__ bns, float* __restrict__ bnb,
                           short* __restrict__ w1h, short* __restrict__ w1l,
                           short* __restrict__ w2h, short* __restrict__ w2l) {
  int blk = blockIdx.x;
  if (blk >= B_ * N_) {
    int tid = (blk - B_ * N_) * 256 + threadIdx.x;   // 0..8191
    int f = tid >> 6, l = tid & 63;
    if (f < 64) {
      int nt = f >> 2, ks = f & 3;
      int n = nt * 16 + (l & 15);
      int kb = ks * 32 + (l >> 4) * 8;
#pragma unroll
      for (int j = 0; j < 8; ++j) {
        float v = w1[(size_t)(kb + j) * 256 + n];
        unsigned short h = f2bf(v);
        w1h[((size_t)f * 64 + l) * 8 + j] = (short)h;
        w1l[((size_t)f * 64 + l) * 8 + j] = (short)f2bf(v - bf2f(h));
      }
    } else {
      int g = f - 64;
      int nt = g >> 3, ks = g & 7;
      int n = nt * 16 + (l & 15);
      int kb = ks * 32 + (l >> 4) * 8;
#pragma unroll
      for (int j = 0; j < 8; ++j) {
        float v = w2[(size_t)(kb + j) * 128 + n];
        unsigned short h = f2bf(v);
        w2h[((size_t)g * 64 + l) * 8 + j] = (short)h;
        w2l[((size_t)g * 64 + l) * 8 + j] = (short)f2bf(v - bf2f(h));
      }
    }
    return;
  }
  int bn = blk;                   // 0..11
  int bb = bn / N_;
  if (bn == 0 && threadIdx.x < FD_) {
    int t = threadIdx.x;
    float inv = 1.0f / sqrtf(bn_v[t] + 1e-5f);
    float sc = bn_g[t] * inv;
    bns[t] = sc;
    bnb[t] = bn_b[t] - bn_m[t] * sc;
  }
  const float* Ep = E + bn * 16;
  double R[9], T[3];
#pragma unroll
  for (int i = 0; i < 3; ++i) {
#pragma unroll
    for (int j = 0; j < 3; ++j) R[i*3+j] = (double)Ep[i*4+j];
    T[i] = (double)Ep[i*4+3];
  }
  double dd = (double)dis[bb];
  double M[9];
#pragma unroll
  for (int i = 0; i < 3; ++i)
#pragma unroll
    for (int j = 0; j < 3; ++j)
      M[i*3+j] = R[i*3+j] - T[i] * (double)nrm[bb*3+j] / dd;
  const float* Is = I_src + bn * 9;
  double A[9];
#pragma unroll
  for (int i = 0; i < 3; ++i)
#pragma unroll
    for (int j = 0; j < 3; ++j)
      A[i*3+j] = (double)Is[i*3+0]*M[0+j] + (double)Is[i*3+1]*M[3+j] + (double)Is[i*3+2]*M[6+j];
  const float* It = I_tar_inv + bb * 9;
  double Hm[9];
#pragma unroll
  for (int i = 0; i < 3; ++i)
#pragma unroll
    for (int j = 0; j < 3; ++j)
      Hm[i*3+j] = A[i*3+0]*(double)It[0+j] + A[i*3+1]*(double)It[3+j] + A[i*3+2]*(double)It[6+j];

  const double dx = 1.0 / (double)(W_ - 1);
  const double dy = 1.0 / (double)(H_ - 1);
  for (int p = threadIdx.x; p < P_; p += 256) {
    int ii = p / W_;
    int jj = p - ii * W_;
    double xs = (jj == W_ - 1) ? 1.0 : (double)jj * dx;   // np.linspace exact endpoint
    double ys = (ii == H_ - 1) ? 1.0 : (double)ii * dy;
    double px = xs * IMGW;
    double py = ys * IMGH;
    double hx = Hm[0]*px + Hm[1]*py + Hm[2];
    double hy = Hm[3]*px + Hm[4]*py + Hm[5];
    double hz = Hm[6]*px + Hm[7]*py + Hm[8];
    double u = ((hx / hz) / IMGW) * (double)W_;
    double v = ((hy / hz) / IMGH) * (double)H_;
    double x0 = floor(u), y0 = floor(v);
    bool valid = (u >= 0.0) && (u <= (double)(W_ - 1)) && (v >= 0.0) && (v <= (double)(H_ - 1));
    int x0i = min(max((int)x0, 0), W_ - 1);
    int x1i = min(x0i + 1, W_ - 1);
    int y0i = min(max((int)y0, 0), H_ - 1);
    int y1i = min(y0i + 1, H_ - 1);
    Samp s;
    s.wx = (float)(u - x0);
    s.wy = (float)(v - y0);
    s.o00 = (y0i * W_ + x0i) * DIM_;
    s.o01 = (y0i * W_ + x1i) * DIM_;
    s.o10 = (y1i * W_ + x0i) * DIM_;
    s.o11 = (y1i * W_ + x1i) * DIM_;
    s.valid = valid ? 1 : 0;
    s.pad = 0;
    samp[(size_t)bn * P_ + p] = s;
  }
}

// ---------------- Kernel B: BN+ReLU+1x1 conv as bf16 MFMA -> val_t[bn][p][o] in BF16 ----------------
__global__ __launch_bounds__(256) void conv_kernel(const float* __restrict__ feature,
    const float* __restrict__ conv_w, const float* __restrict__ bns_g, const float* __restrict__ bnb_g,
    unsigned short* __restrict__ val_t) {
  __shared__ __align__(16) short w_lds[128 * 136];  // 34816 B
  __shared__ __align__(16) short xhi[128 * 66];     // 16896 B
  __shared__ __align__(16) short xlo[128 * 66];     // 16896 B
  __shared__ float bns_s[FD_], bnb_s[FD_];
  int t = threadIdx.x;

#pragma unroll
  for (int k = 0; k < 16; ++k) {
    int f4 = t + 256 * k;
    int o  = f4 >> 5;
    int c4 = (f4 & 31) * 4;
    float4 w = *(const float4*)(conv_w + (size_t)f4 * 4);
    short* dst = &w_lds[o * 136 + c4];
    dst[0] = (short)f2bf(w.x); dst[1] = (short)f2bf(w.y);
    dst[2] = (short)f2bf(w.z); dst[3] = (short)f2bf(w.w);
  }
  if (t < FD_) { bns_s[t] = bns_g[t]; bnb_s[t] = bnb_g[t]; }
  __syncthreads();

  int bn = blockIdx.y;
  int p0 = blockIdx.x * 64;
  const float* fb = feature + (size_t)bn * FD_ * P_ + p0;

#pragma unroll
  for (int k = 0; k < 8; ++k) {
    int f4 = t + 256 * k;
    int c  = f4 >> 4;
    int pq = (f4 & 15) * 4;
    float4 x = *(const float4*)(fb + (size_t)c * P_ + pq);
    float s = bns_s[c], o = bnb_s[c];
    float v0 = fmaxf(x.x * s + o, 0.f);
    float v1 = fmaxf(x.y * s + o, 0.f);
    float v2 = fmaxf(x.z * s + o, 0.f);
    float v3 = fmaxf(x.w * s + o, 0.f);
    unsigned short h0 = f2bf(v0), h1 = f2bf(v1), h2 = f2bf(v2), h3 = f2bf(v3);
    unsigned short l0 = f2bf(v0 - bf2f(h0)), l1 = f2bf(v1 - bf2f(h1));
    unsigned short l2 = f2bf(v2 - bf2f(h2)), l3 = f2bf(v3 - bf2f(h3));
    short* dh = &xhi[c * 66 + pq];
    short* dl = &xlo[c * 66 + pq];
    dh[0] = (short)h0; dh[1] = (short)h1; dh[2] = (short)h2; dh[3] = (short)h3;
    dl[0] = (short)l0; dl[1] = (short)l1; dl[2] = (short)l2; dl[3] = (short)l3;
  }
  __syncthreads();

  int lane = t & 63, wv = t >> 6;
  int m = lane & 15, quad = lane >> 4;
  int pw = wv * 16;

  short8 Ah[4], Al[4];
#pragma unroll
  for (int ks = 0; ks < 4; ++ks) {
#pragma unroll
    for (int j = 0; j < 8; ++j) {
      int c = ks * 32 + quad * 8 + j;
      Ah[ks][j] = xhi[c * 66 + pw + m];
      Al[ks][j] = xlo[c * 66 + pw + m];
    }
  }

  f32x4 acc[8];
#pragma unroll
  for (int ot = 0; ot < 8; ++ot) {
    f32x4 a = {0.f, 0.f, 0.f, 0.f};
#pragma unroll
    for (int ks = 0; ks < 4; ++ks) {
      short8 Bv = *(const short8*)&w_lds[(ot * 16 + m) * 136 + ks * 32 + quad * 8];
      a = __builtin_amdgcn_mfma_f32_16x16x32_bf16(Ah[ks], Bv, a, 0, 0, 0);
      a = __builtin_amdgcn_mfma_f32_16x16x32_bf16(Al[ks], Bv, a, 0, 0, 0);
    }
    acc[ot] = a;
  }

  unsigned short* vb = val_t + ((size_t)bn * P_ + p0 + pw + quad * 4) * DIM_ + m;
#pragma unroll
  for (int ot = 0; ot < 8; ++ot)
#pragma unroll
    for (int r = 0; r < 4; ++r)
      vb[(size_t)r * DIM_ + ot * 16] = f2bf(acc[ot][r]);
}

// ---------------- Kernel C: warp-per-point bilinear attention + LN1 (bf16 val_t, XCD swizzle) ----------------
__global__ __launch_bounds__(256) void attn_kernel(const unsigned short* __restrict__ val_t,
    const Samp* __restrict__ samp,
    const float* __restrict__ ln1g, const float* __restrict__ ln1b,
    float* __restrict__ zln) {
  int lane = threadIdx.x & 63;
  int wv = threadIdx.x >> 6;
  // XCD-aware swizzle: blocks == k (mod 8) go to XCD k; give each XCD a contiguous point band
  int bid = blockIdx.x;
  int newbid = (bid & 7) * (gridDim.x >> 3) + (bid >> 3);
  int pt = newbid * 4 + wv;
  if (pt >= B_ * P_) return;
  int bb = pt / P_;
  int p = pt - bb * P_;
  int d0 = lane << 1;

  unsigned int uq = *(const unsigned int*)(val_t + ((size_t)(bb * N_) * P_ + p) * DIM_ + d0);
  float qx = bf2f((unsigned short)(uq & 0xffffu));
  float qy = bf2f((unsigned short)(uq >> 16));
  float qss = wave_sum(qx * qx + qy * qy);
  float qinv = 1.0f / fmaxf(sqrtf(qss), 1e-12f);
  float qn0 = qx * qinv, qn1 = qy * qinv;

  float dots[N_], vs0[N_], vs1[N_];
#pragma unroll
  for (int n = 0; n < N_; ++n) {
    Samp s = samp[(size_t)(bb * N_ + n) * P_ + p];
    const unsigned short* base = val_t + (size_t)(bb * N_ + n) * P_ * DIM_ + d0;
    unsigned int u00 = *(const unsigned int*)(base + s.o00);
    unsigned int u01 = *(const unsigned int*)(base + s.o01);
    unsigned int u10 = *(const unsigned int*)(base + s.o10);
    unsigned int u11 = *(const unsigned int*)(base + s.o11);
    float wx = s.wx, wy = s.wy;
    float w00 = (1.0f - wx) * (1.0f - wy), w01 = wx * (1.0f - wy);
    float w10 = (1.0f - wx) * wy,          w11 = wx * wy;
    float v0 = bf2f((unsigned short)(u00 & 0xffffu)) * w00 + bf2f((unsigned short)(u01 & 0xffffu)) * w01
             + bf2f((unsigned short)(u10 & 0xffffu)) * w10 + bf2f((unsigned short)(u11 & 0xffffu)) * w11;
    float v1 = bf2f((unsigned short)(u00 >> 16)) * w00 + bf2f((unsigned short)(u01 >> 16)) * w01
             + bf2f((unsigned short)(u10 >> 16)) * w10 + bf2f((unsigned short)(u11 >> 16)) * w11;
    float ss = wave_sum(v0 * v0 + v1 * v1);
    float kinv = 1.0f / fmaxf(sqrtf(ss), 1e-12f);
    float dt = wave_sum(qn0 * (v0 * kinv) + qn1 * (v1 * kinv));
    dots[n] = s.valid ? dt : 0.0f;
    vs0[n] = v0; vs1[n] = v1;
  }
  float mx = dots[0];
#pragma unroll
  for (int n = 1; n < N_; ++n) mx = fmaxf(mx, dots[n]);
  float es[N_], den = 0.f;
#pragma unroll
  for (int n = 0; n < N_; ++n) { es[n] = expf(dots[n] - mx); den += es[n]; }
  float dinv = 1.0f / den;
  float z0 = qx, z1 = qy;
#pragma unroll
  for (int n = 0; n < N_; ++n) { float a = es[n] * dinv; z0 += a * vs0[n]; z1 += a * vs1[n]; }
  float mean = wave_sum(z0 + z1) * (1.0f / DIM_);
  float c0 = z0 - mean, c1 = z1 - mean;
  float var = wave_sum(c0 * c0 + c1 * c1) * (1.0f / DIM_);
  float rstd = rsqrtf(var + 1e-5f);
  float o0 = c0 * rstd * ln1g[d0]     + ln1b[d0];
  float o1 = c1 * rstd * ln1g[d0 + 1] + ln1b[d0 + 1];
  *(float2*)(zln + (size_t)pt * DIM_ + d0) = make_float2(o0, o1);
}

// ---------------- Kernel D: MLP via bf16 MFMA (3-term hi/lo), split-N halves, 34.8 KB LDS ----------------
__global__ __launch_bounds__(256) void mlp_kernel(const float* __restrict__ zln,
    const short* __restrict__ w1h, const short* __restrict__ w1l,
    const short* __restrict__ w2h, const short* __restrict__ w2l,
    const float* __restrict__ b1, const float* __restrict__ b2,
    const float* __restrict__ ln2g, const float* __restrict__ ln2b,
    float* __restrict__ out) {
  __shared__ __align__(16) char smem[34816];
  int t = threadIdx.x;
  int row0 = blockIdx.x * 64;

  // ---- phase 1: zl tile (64 x 128, stride 132) ----
  float* zl = (float*)smem;
#pragma unroll
  for (int k = 0; k < 8; ++k) {
    int idx = t + 256 * k;        // 0..2047 float4s
    int r = idx >> 5, c4 = (idx & 31) * 4;
    *(float4*)&zl[r * 132 + c4] = *(const float4*)(zln + (size_t)(row0 + r) * DIM_ + c4);
  }
  __syncthreads();

  int lane = t & 63, wv = t >> 6, m = lane & 15, quad = lane >> 4;
  int pw = wv * 16;

  // A1 frags (hi/lo) from zl
  short8 A1h[4], A1l[4];
#pragma unroll
  for (int ks = 0; ks < 4; ++ks) {
    const float* zr = &zl[(pw + m) * 132 + ks * 32 + quad * 8];
#pragma unroll
    for (int j = 0; j < 8; ++j) {
      float v = zr[j];
      unsigned short h = f2bf(v);
      A1h[ks][j] = (short)h;
      A1l[ks][j] = (short)f2bf(v - bf2f(h));
    }
  }
  // residual to registers (C-layout positions this lane will own)
  float res[8][4];
#pragma unroll
  for (int nt = 0; nt < 8; ++nt)
#pragma unroll
    for (int r = 0; r < 4; ++r)
      res[nt][r] = zl[(pw + quad * 4 + r) * 132 + nt * 16 + m];

  float b1v[16];
#pragma unroll
  for (int nt = 0; nt < 16; ++nt) b1v[nt] = b1[nt * 16 + m];
  float b2v[8], g2v[8], be2v[8];
#pragma unroll
  for (int nt = 0; nt < 8; ++nt) {
    b2v[nt] = b2[nt * 16 + m];
    g2v[nt] = ln2g[nt * 16 + m];
    be2v[nt] = ln2b[nt * 16 + m];
  }
  __syncthreads();   // zl dead; smem becomes hdn

  // ---- phase 2: hdn halves (per-wave 16 x 136 shorts; hi at [0,17408), lo at [17408,34816)) ----
  short* hh = (short*)smem + wv * (16 * 136);
  short* hl = (short*)(smem + 17408) + wv * (16 * 136);

  f32x4 acc2[8];
#pragma unroll
  for (int nt = 0; nt < 8; ++nt) acc2[nt] = (f32x4){0.f, 0.f, 0.f, 0.f};

#pragma unroll
  for (int half = 0; half < 2; ++half) {
    if (half) __syncthreads();   // protect previous half's reads from this half's writes (WAR)
#pragma unroll
    for (int ntl = 0; ntl < 8; ++ntl) {
      int nt = half * 8 + ntl;
      f32x4 a = {0.f, 0.f, 0.f, 0.f};
#pragma unroll
      for (int ks = 0; ks < 4; ++ks) {
        short8 Bh = *(const short8*)(w1h + ((size_t)(nt * 4 + ks) * 64 + lane) * 8);
        short8 Bl = *(const short8*)(w1l + ((size_t)(nt * 4 + ks) * 64 + lane) * 8);
        a = __builtin_amdgcn_mfma_f32_16x16x32_bf16(A1h[ks], Bh, a, 0, 0, 0);
        a = __builtin_amdgcn_mfma_f32_16x16x32_bf16(A1l[ks], Bh, a, 0, 0, 0);
        a = __builtin_amdgcn_mfma_f32_16x16x32_bf16(A1h[ks], Bl, a, 0, 0, 0);
      }
#pragma unroll
      for (int r = 0; r < 4; ++r) {
        float hv = a[r] + b1v[nt];
        float g = 0.5f * hv * (1.0f + erff(hv * 0.70710678118654752f));
        unsigned short gh = f2bf(g);
        int addr = (quad * 4 + r) * 136 + ntl * 16 + m;
        hh[addr] = (short)gh;
        hl[addr] = (short)f2bf(g - bf2f(gh));
      }
    }
    __syncthreads();   // writes ordered before reads
#pragma unroll
    for (int ks2 = 0; ks2 < 4; ++ks2) {
      short8 A2h = *(const short8*)&hh[m * 136 + ks2 * 32 + quad * 8];
      short8 A2l = *(const short8*)&hl[m * 136 + ks2 * 32 + quad * 8];
#pragma unroll
      for (int nt = 0; nt < 8; ++nt) {
        int g = nt * 8 + half * 4 + ks2;
        short8 Bh = *(const short8*)(w2h + ((size_t)g * 64 + lane) * 8);
        short8 Bl = *(const short8*)(w2l + ((size_t)g * 64 + lane) * 8);
        acc2[nt] = __builtin_amdgcn_mfma_f32_16x16x32_bf16(A2h, Bh, acc2[nt], 0, 0, 0);
        acc2[nt] = __builtin_amdgcn_mfma_f32_16x16x32_bf16(A2l, Bh, acc2[nt], 0, 0, 0);
        acc2[nt] = __builtin_amdgcn_mfma_f32_16x16x32_bf16(A2h, Bl, acc2[nt], 0, 0, 0);
      }
    }
  }

  // bias + residual + LN2 (per-pixel stats via m-group shuffles)
  float z2[8][4], mean[4], rstd[4];
#pragma unroll
  for (int r = 0; r < 4; ++r) {
    float s = 0.f;
#pragma unroll
    for (int nt = 0; nt < 8; ++nt) {
      float v = acc2[nt][r] + b2v[nt] + res[nt][r];
      z2[nt][r] = v;
      s += v;
    }
    s += __shfl_xor(s, 1, 64); s += __shfl_xor(s, 2, 64);
    s += __shfl_xor(s, 4, 64); s += __shfl_xor(s, 8, 64);
    mean[r] = s * (1.0f / 128.0f);
    float vv = 0.f;
#pragma unroll
    for (int nt = 0; nt < 8; ++nt) { float d = z2[nt][r] - mean[r]; vv += d * d; }
    vv += __shfl_xor(vv, 1, 64); vv += __shfl_xor(vv, 2, 64);
    vv += __shfl_xor(vv, 4, 64); vv += __shfl_xor(vv, 8, 64);
    rstd[r] = rsqrtf(vv * (1.0f / 128.0f) + 1e-5f);
  }

  __syncthreads();   // all hdn reads done before zo overlay
  // ---- phase 3: zo transpose buffer (128 x 68 floats) ----
  float* zo = (float*)smem;
#pragma unroll
  for (int nt = 0; nt < 8; ++nt)
#pragma unroll
    for (int r = 0; r < 4; ++r) {
      float v = (z2[nt][r] - mean[r]) * rstd[r] * g2v[nt] + be2v[nt];
      zo[(nt * 16 + m) * 68 + pw + quad * 4 + r] = v;
    }
  __syncthreads();

  // coalesced transposed store: out[b][d][p]
  int bb2 = row0 / P_;
  int p0 = row0 - bb2 * P_;
#pragma unroll
  for (int it = 0; it < 8; ++it) {
    int d = it * 16 + (t >> 4);
    int pq = (t & 15) * 4;
    float4 v4 = *(float4*)&zo[d * 68 + pq];
    *(float4*)(out + (size_t)bb2 * DIM_ * P_ + (size_t)d * P_ + p0 + pq) = v4;
  }
}

extern "C" void kernel_launch(void* const* d_in, const int* in_sizes, int n_in,
                              void* d_out, int out_size, void* d_ws, size_t ws_size,
                              hipStream_t stream) {
  const float* feature = (const float*)d_in[0];
  const float* I_src   = (const float*)d_in[1];
  const float* I_tar   = (const float*)d_in[2];
  const float* E       = (const float*)d_in[3];
  const float* dis     = (const float*)d_in[4];
  const float* nrm     = (const float*)d_in[5];
  const float* conv_w  = (const float*)d_in[6];
  const float* bn_g    = (const float*)d_in[7];
  const float* bn_b    = (const float*)d_in[8];
  const float* bn_m    = (const float*)d_in[9];
  const float* bn_v    = (const float*)d_in[10];
  const float* ln1g    = (const float*)d_in[11];
  const float* ln1b    = (const float*)d_in[12];
  const float* ln2g    = (const float*)d_in[13];
  const float* ln2b    = (const float*)d_in[14];
  const float* w1      = (const float*)d_in[15];
  const float* b1      = (const float*)d_in[16];
  const float* w2      = (const float*)d_in[17];
  const float* b2      = (const float*)d_in[18];
  float* out = (float*)d_out;

  float* wsf = (float*)d_ws;
  float* bns = wsf;                   // 128
  float* bnb = wsf + 128;             // 128
  unsigned short* val_t = (unsigned short*)(wsf + 256);          // B*N*P*DIM bf16 (34.6 MB)
  float* zln = (float*)(val_t + (size_t)B_ * N_ * P_ * DIM_);    // B*P*DIM floats
  Samp*  samp = (Samp*)(zln + (size_t)B_ * P_ * DIM_);           // 12*P structs (32B each)
  short* w1h = (short*)(samp + (size_t)B_ * N_ * P_);            // 32768 shorts each
  short* w1l = w1h + 32768;
  short* w2h = w1l + 32768;
  short* w2l = w2h + 32768;

  hipLaunchKernelGGL(prep_kernel, dim3(B_ * N_ + 32), dim3(256), 0, stream,
                     I_src, I_tar, E, dis, nrm, bn_g, bn_b, bn_m, bn_v, w1, w2,
                     samp, bns, bnb, w1h, w1l, w2h, w2l);
  hipLaunchKernelGGL(conv_kernel, dim3(P_ / 64, B_ * N_), dim3(256), 0, stream,
                     feature, conv_w, bns, bnb, val_t);
  hipLaunchKernelGGL(attn_kernel, dim3(B_ * P_ / 4), dim3(256), 0, stream,
                     val_t, samp, ln1g, ln1b, zln);
  hipLaunchKernelGGL(mlp_kernel, dim3(B_ * P_ / 64), dim3(256), 0, stream,
                     zln, w1h, w1l, w2h, w2l, b1, b2, ln2g, ln2b, out);
}

// Round 10
// 219.899 us; speedup vs baseline: 1.2778x; 1.0655x over previous
//
#include <hip/hip_runtime.h>
#include <cstdint>
#include <cstddef>

#define B_   2
#define N_   6
#define FD_  128
#define DIM_ 128
#define H_   64
#define W_   176
#define P_   (H_*W_)      // 11264
#define IMGW 704.0
#define IMGH 256.0

struct __align__(16) Samp { float wx, wy; int o00, o01; int o10, o11; int valid, pad; };

typedef __attribute__((ext_vector_type(8))) short short8;
typedef __attribute__((ext_vector_type(4))) float f32x4;

__device__ __forceinline__ float wave_sum(float v) {
#pragma unroll
  for (int off = 32; off > 0; off >>= 1) v += __shfl_xor(v, off, 64);
  return v;
}

__device__ __forceinline__ unsigned short f2bf(float f) {
  unsigned int u = __float_as_uint(f);
  unsigned int r = (u + 0x7fffu + ((u >> 16) & 1u)) >> 16;
  return (unsigned short)r;
}
__device__ __forceinline__ float bf2f(unsigned short s) {
  return __uint_as_float(((unsigned int)s) << 16);
}

// ---------------- Kernel A: fp64 homography -> sample descriptors; BN fold; MLP weight pre-swizzle ----------------
// blocks 0..11: uv work. blocks 12..43: wprep (128 frags x 64 lanes, single bf16).
__global__ __launch_bounds__(256) void prep_kernel(const float* __restrict__ I_src, const float* __restrict__ I_tar_inv,
                           const float* __restrict__ E, const float* __restrict__ dis,
                           const float* __restrict__ nrm,
                           const float* __restrict__ bn_g, const float* __restrict__ bn_b,
                           const float* __restrict__ bn_m, const float* __restrict__ bn_v,
                           const float* __restrict__ w1, const float* __restrict__ w2,
                           Samp* __restrict__ samp, float* __restrict__ bns, float* __restrict__ bnb,
                           short* __restrict__ w1b, short* __restrict__ w2b) {
  int blk = blockIdx.x;
  if (blk >= B_ * N_) {
    int tid = (blk - B_ * N_) * 256 + threadIdx.x;   // 0..8191
    int f = tid >> 6, l = tid & 63;
    if (f < 64) {
      int nt = f >> 2, ks = f & 3;
      int n = nt * 16 + (l & 15);
      int kb = ks * 32 + (l >> 4) * 8;
#pragma unroll
      for (int j = 0; j < 8; ++j)
        w1b[((size_t)f * 64 + l) * 8 + j] = (short)f2bf(w1[(size_t)(kb + j) * 256 + n]);
    } else {
      int g = f - 64;
      int nt = g >> 3, ks = g & 7;
      int n = nt * 16 + (l & 15);
      int kb = ks * 32 + (l >> 4) * 8;
#pragma unroll
      for (int j = 0; j < 8; ++j)
        w2b[((size_t)g * 64 + l) * 8 + j] = (short)f2bf(w2[(size_t)(kb + j) * 128 + n]);
    }
    return;
  }
  int bn = blk;                   // 0..11
  int bb = bn / N_;
  if (bn == 0 && threadIdx.x < FD_) {
    int t = threadIdx.x;
    float inv = 1.0f / sqrtf(bn_v[t] + 1e-5f);
    float sc = bn_g[t] * inv;
    bns[t] = sc;
    bnb[t] = bn_b[t] - bn_m[t] * sc;
  }
  const float* Ep = E + bn * 16;
  double R[9], T[3];
#pragma unroll
  for (int i = 0; i < 3; ++i) {
#pragma unroll
    for (int j = 0; j < 3; ++j) R[i*3+j] = (double)Ep[i*4+j];
    T[i] = (double)Ep[i*4+3];
  }
  double dd = (double)dis[bb];
  double M[9];
#pragma unroll
  for (int i = 0; i < 3; ++i)
#pragma unroll
    for (int j = 0; j < 3; ++j)
      M[i*3+j] = R[i*3+j] - T[i] * (double)nrm[bb*3+j] / dd;
  const float* Is = I_src + bn * 9;
  double A[9];
#pragma unroll
  for (int i = 0; i < 3; ++i)
#pragma unroll
    for (int j = 0; j < 3; ++j)
      A[i*3+j] = (double)Is[i*3+0]*M[0+j] + (double)Is[i*3+1]*M[3+j] + (double)Is[i*3+2]*M[6+j];
  const float* It = I_tar_inv + bb * 9;
  double Hm[9];
#pragma unroll
  for (int i = 0; i < 3; ++i)
#pragma unroll
    for (int j = 0; j < 3; ++j)
      Hm[i*3+j] = A[i*3+0]*(double)It[0+j] + A[i*3+1]*(double)It[3+j] + A[i*3+2]*(double)It[6+j];

  const double dx = 1.0 / (double)(W_ - 1);
  const double dy = 1.0 / (double)(H_ - 1);
  for (int p = threadIdx.x; p < P_; p += 256) {
    int ii = p / W_;
    int jj = p - ii * W_;
    double xs = (jj == W_ - 1) ? 1.0 : (double)jj * dx;   // np.linspace exact endpoint
    double ys = (ii == H_ - 1) ? 1.0 : (double)ii * dy;
    double px = xs * IMGW;
    double py = ys * IMGH;
    double hx = Hm[0]*px + Hm[1]*py + Hm[2];
    double hy = Hm[3]*px + Hm[4]*py + Hm[5];
    double hz = Hm[6]*px + Hm[7]*py + Hm[8];
    double u = ((hx / hz) / IMGW) * (double)W_;
    double v = ((hy / hz) / IMGH) * (double)H_;
    double x0 = floor(u), y0 = floor(v);
    bool valid = (u >= 0.0) && (u <= (double)(W_ - 1)) && (v >= 0.0) && (v <= (double)(H_ - 1));
    int x0i = min(max((int)x0, 0), W_ - 1);
    int x1i = min(x0i + 1, W_ - 1);
    int y0i = min(max((int)y0, 0), H_ - 1);
    int y1i = min(y0i + 1, H_ - 1);
    Samp s;
    s.wx = (float)(u - x0);
    s.wy = (float)(v - y0);
    s.o00 = (y0i * W_ + x0i) * DIM_;
    s.o01 = (y0i * W_ + x1i) * DIM_;
    s.o10 = (y1i * W_ + x0i) * DIM_;
    s.o11 = (y1i * W_ + x1i) * DIM_;
    s.valid = valid ? 1 : 0;
    s.pad = 0;
    samp[(size_t)bn * P_ + p] = s;
  }
}

// ---------------- Kernel B: BN+ReLU+1x1 conv as bf16 MFMA -> val_t[bn][p][o] in BF16 ----------------
__global__ __launch_bounds__(256) void conv_kernel(const float* __restrict__ feature,
    const float* __restrict__ conv_w, const float* __restrict__ bns_g, const float* __restrict__ bnb_g,
    unsigned short* __restrict__ val_t) {
  __shared__ __align__(16) short w_lds[128 * 136];  // 34816 B
  __shared__ __align__(16) short xhi[128 * 66];     // 16896 B
  __shared__ __align__(16) short xlo[128 * 66];     // 16896 B
  __shared__ float bns_s[FD_], bnb_s[FD_];
  int t = threadIdx.x;

#pragma unroll
  for (int k = 0; k < 16; ++k) {
    int f4 = t + 256 * k;
    int o  = f4 >> 5;
    int c4 = (f4 & 31) * 4;
    float4 w = *(const float4*)(conv_w + (size_t)f4 * 4);
    short* dst = &w_lds[o * 136 + c4];
    dst[0] = (short)f2bf(w.x); dst[1] = (short)f2bf(w.y);
    dst[2] = (short)f2bf(w.z); dst[3] = (short)f2bf(w.w);
  }
  if (t < FD_) { bns_s[t] = bns_g[t]; bnb_s[t] = bnb_g[t]; }
  __syncthreads();

  int bn = blockIdx.y;
  int p0 = blockIdx.x * 64;
  const float* fb = feature + (size_t)bn * FD_ * P_ + p0;

#pragma unroll
  for (int k = 0; k < 8; ++k) {
    int f4 = t + 256 * k;
    int c  = f4 >> 4;
    int pq = (f4 & 15) * 4;
    float4 x = *(const float4*)(fb + (size_t)c * P_ + pq);
    float s = bns_s[c], o = bnb_s[c];
    float v0 = fmaxf(x.x * s + o, 0.f);
    float v1 = fmaxf(x.y * s + o, 0.f);
    float v2 = fmaxf(x.z * s + o, 0.f);
    float v3 = fmaxf(x.w * s + o, 0.f);
    unsigned short h0 = f2bf(v0), h1 = f2bf(v1), h2 = f2bf(v2), h3 = f2bf(v3);
    unsigned short l0 = f2bf(v0 - bf2f(h0)), l1 = f2bf(v1 - bf2f(h1));
    unsigned short l2 = f2bf(v2 - bf2f(h2)), l3 = f2bf(v3 - bf2f(h3));
    short* dh = &xhi[c * 66 + pq];
    short* dl = &xlo[c * 66 + pq];
    dh[0] = (short)h0; dh[1] = (short)h1; dh[2] = (short)h2; dh[3] = (short)h3;
    dl[0] = (short)l0; dl[1] = (short)l1; dl[2] = (short)l2; dl[3] = (short)l3;
  }
  __syncthreads();

  int lane = t & 63, wv = t >> 6;
  int m = lane & 15, quad = lane >> 4;
  int pw = wv * 16;

  short8 Ah[4], Al[4];
#pragma unroll
  for (int ks = 0; ks < 4; ++ks) {
#pragma unroll
    for (int j = 0; j < 8; ++j) {
      int c = ks * 32 + quad * 8 + j;
      Ah[ks][j] = xhi[c * 66 + pw + m];
      Al[ks][j] = xlo[c * 66 + pw + m];
    }
  }

  f32x4 acc[8];
#pragma unroll
  for (int ot = 0; ot < 8; ++ot) {
    f32x4 a = {0.f, 0.f, 0.f, 0.f};
#pragma unroll
    for (int ks = 0; ks < 4; ++ks) {
      short8 Bv = *(const short8*)&w_lds[(ot * 16 + m) * 136 + ks * 32 + quad * 8];
      a = __builtin_amdgcn_mfma_f32_16x16x32_bf16(Ah[ks], Bv, a, 0, 0, 0);
      a = __builtin_amdgcn_mfma_f32_16x16x32_bf16(Al[ks], Bv, a, 0, 0, 0);
    }
    acc[ot] = a;
  }

  unsigned short* vb = val_t + ((size_t)bn * P_ + p0 + pw + quad * 4) * DIM_ + m;
#pragma unroll
  for (int ot = 0; ot < 8; ++ot)
#pragma unroll
    for (int r = 0; r < 4; ++r)
      vb[(size_t)r * DIM_ + ot * 16] = f2bf(acc[ot][r]);
}

// ---------------- Kernel C: warp-per-point bilinear attention + LN1 (bf16 val_t, XCD swizzle) ----------------
__global__ __launch_bounds__(256) void attn_kernel(const unsigned short* __restrict__ val_t,
    const Samp* __restrict__ samp,
    const float* __restrict__ ln1g, const float* __restrict__ ln1b,
    float* __restrict__ zln) {
  int lane = threadIdx.x & 63;
  int wv = threadIdx.x >> 6;
  int bid = blockIdx.x;
  int newbid = (bid & 7) * (gridDim.x >> 3) + (bid >> 3);
  int pt = newbid * 4 + wv;
  if (pt >= B_ * P_) return;
  int bb = pt / P_;
  int p = pt - bb * P_;
  int d0 = lane << 1;

  unsigned int uq = *(const unsigned int*)(val_t + ((size_t)(bb * N_) * P_ + p) * DIM_ + d0);
  float qx = bf2f((unsigned short)(uq & 0xffffu));
  float qy = bf2f((unsigned short)(uq >> 16));
  float qss = wave_sum(qx * qx + qy * qy);
  float qinv = 1.0f / fmaxf(sqrtf(qss), 1e-12f);
  float qn0 = qx * qinv, qn1 = qy * qinv;

  float dots[N_], vs0[N_], vs1[N_];
#pragma unroll
  for (int n = 0; n < N_; ++n) {
    Samp s = samp[(size_t)(bb * N_ + n) * P_ + p];
    const unsigned short* base = val_t + (size_t)(bb * N_ + n) * P_ * DIM_ + d0;
    unsigned int u00 = *(const unsigned int*)(base + s.o00);
    unsigned int u01 = *(const unsigned int*)(base + s.o01);
    unsigned int u10 = *(const unsigned int*)(base + s.o10);
    unsigned int u11 = *(const unsigned int*)(base + s.o11);
    float wx = s.wx, wy = s.wy;
    float w00 = (1.0f - wx) * (1.0f - wy), w01 = wx * (1.0f - wy);
    float w10 = (1.0f - wx) * wy,          w11 = wx * wy;
    float v0 = bf2f((unsigned short)(u00 & 0xffffu)) * w00 + bf2f((unsigned short)(u01 & 0xffffu)) * w01
             + bf2f((unsigned short)(u10 & 0xffffu)) * w10 + bf2f((unsigned short)(u11 & 0xffffu)) * w11;
    float v1 = bf2f((unsigned short)(u00 >> 16)) * w00 + bf2f((unsigned short)(u01 >> 16)) * w01
             + bf2f((unsigned short)(u10 >> 16)) * w10 + bf2f((unsigned short)(u11 >> 16)) * w11;
    float ss = wave_sum(v0 * v0 + v1 * v1);
    float kinv = 1.0f / fmaxf(sqrtf(ss), 1e-12f);
    float dt = wave_sum(qn0 * (v0 * kinv) + qn1 * (v1 * kinv));
    dots[n] = s.valid ? dt : 0.0f;
    vs0[n] = v0; vs1[n] = v1;
  }
  float mx = dots[0];
#pragma unroll
  for (int n = 1; n < N_; ++n) mx = fmaxf(mx, dots[n]);
  float es[N_], den = 0.f;
#pragma unroll
  for (int n = 0; n < N_; ++n) { es[n] = expf(dots[n] - mx); den += es[n]; }
  float dinv = 1.0f / den;
  float z0 = qx, z1 = qy;
#pragma unroll
  for (int n = 0; n < N_; ++n) { float a = es[n] * dinv; z0 += a * vs0[n]; z1 += a * vs1[n]; }
  float mean = wave_sum(z0 + z1) * (1.0f / DIM_);
  float c0 = z0 - mean, c1 = z1 - mean;
  float var = wave_sum(c0 * c0 + c1 * c1) * (1.0f / DIM_);
  float rstd = rsqrtf(var + 1e-5f);
  float o0 = c0 * rstd * ln1g[d0]     + ln1b[d0];
  float o1 = c1 * rstd * ln1g[d0 + 1] + ln1b[d0 + 1];
  *(float2*)(zln + (size_t)pt * DIM_ + d0) = make_float2(o0, o1);
}

// ---------------- Kernel D: MLP via bf16 MFMA (act hi/lo x W bf16), 8 waves/block, split-N halves ----------------
// 512 thr = 8 waves; wave = (pt = wv&3 px-tile, ng = wv>>2 n-group). 34.8 KB LDS; 352 blocks x 8 = 2816 waves.
// hdn block-shared (64 px x 136 shorts, hi/lo halves); all cross-wave reuse barrier-separated, write-once.
__global__ __launch_bounds__(512) void mlp_kernel(const float* __restrict__ zln,
    const short* __restrict__ w1b, const short* __restrict__ w2b,
    const float* __restrict__ b1, const float* __restrict__ b2,
    const float* __restrict__ ln2g, const float* __restrict__ ln2b,
    float* __restrict__ out) {
  __shared__ __align__(16) char smem[34816];
  int t = threadIdx.x;
  int row0 = blockIdx.x * 64;

  // ---- phase 1: zl tile (64 x 128, stride 132) ----
  float* zl = (float*)smem;
#pragma unroll
  for (int k = 0; k < 4; ++k) {
    int idx = t + 512 * k;        // 0..2047 float4s
    int r = idx >> 5, c4 = (idx & 31) * 4;
    *(float4*)&zl[r * 132 + c4] = *(const float4*)(zln + (size_t)(row0 + r) * DIM_ + c4);
  }
  __syncthreads();

  int lane = t & 63, wv = t >> 6, m = lane & 15, quad = lane >> 4;
  int pt = wv & 3, ng = wv >> 2;
  int pw = pt * 16;

  // A1 frags (hi/lo) from zl (waves with same pt duplicate this — fine)
  short8 A1h[4], A1l[4];
#pragma unroll
  for (int ks = 0; ks < 4; ++ks) {
    const float* zr = &zl[(pw + m) * 132 + ks * 32 + quad * 8];
#pragma unroll
    for (int j = 0; j < 8; ++j) {
      float v = zr[j];
      unsigned short h = f2bf(v);
      A1h[ks][j] = (short)h;
      A1l[ks][j] = (short)f2bf(v - bf2f(h));
    }
  }
  // residual for this wave's out tiles (nt_out = ng*4+i)
  float res[4][4];
#pragma unroll
  for (int i = 0; i < 4; ++i)
#pragma unroll
    for (int r = 0; r < 4; ++r)
      res[i][r] = zl[(pw + quad * 4 + r) * 132 + (ng * 4 + i) * 16 + m];

  float b1v[2][4];
#pragma unroll
  for (int h = 0; h < 2; ++h)
#pragma unroll
    for (int i = 0; i < 4; ++i) b1v[h][i] = b1[(h * 8 + ng * 4 + i) * 16 + m];
  float b2v[4], g2v[4], be2v[4];
#pragma unroll
  for (int i = 0; i < 4; ++i) {
    int d = (ng * 4 + i) * 16 + m;
    b2v[i] = b2[d]; g2v[i] = ln2g[d]; be2v[i] = ln2b[d];
  }
  __syncthreads();   // zl dead; smem becomes hdn

  // ---- phase 2: hdn (block-shared): hh 64x136 shorts at [0,17408), hl at [17408,34816) ----
  short* hh = (short*)smem;
  short* hl = (short*)(smem + 17408);

  f32x4 acc2[4];
#pragma unroll
  for (int i = 0; i < 4; ++i) acc2[i] = (f32x4){0.f, 0.f, 0.f, 0.f};

#pragma unroll
  for (int h = 0; h < 2; ++h) {
    if (h) __syncthreads();   // WAR: previous half's reads before this half's writes
    // GEMM1: this wave's 4 hidden tiles of this half
#pragma unroll
    for (int i = 0; i < 4; ++i) {
      int nt = h * 8 + ng * 4 + i;
      f32x4 a = {0.f, 0.f, 0.f, 0.f};
#pragma unroll
      for (int ks = 0; ks < 4; ++ks) {
        short8 Bv = *(const short8*)(w1b + ((size_t)(nt * 4 + ks) * 64 + lane) * 8);
        a = __builtin_amdgcn_mfma_f32_16x16x32_bf16(A1h[ks], Bv, a, 0, 0, 0);
        a = __builtin_amdgcn_mfma_f32_16x16x32_bf16(A1l[ks], Bv, a, 0, 0, 0);
      }
#pragma unroll
      for (int r = 0; r < 4; ++r) {
        float hv = a[r] + b1v[h][i];
        float g = 0.5f * hv * (1.0f + erff(hv * 0.70710678118654752f));
        unsigned short gh = f2bf(g);
        int addr = (pw + quad * 4 + r) * 136 + (ng * 4 + i) * 16 + m;
        hh[addr] = (short)gh;
        hl[addr] = (short)f2bf(g - bf2f(gh));
      }
    }
    __syncthreads();   // all GEMM1 writes visible before GEMM2 reads (cross-wave)
    // GEMM2 partial over this half's k-range
#pragma unroll
    for (int ks2 = 0; ks2 < 4; ++ks2) {
      short8 A2h = *(const short8*)&hh[(pw + m) * 136 + ks2 * 32 + quad * 8];
      short8 A2l = *(const short8*)&hl[(pw + m) * 136 + ks2 * 32 + quad * 8];
#pragma unroll
      for (int i = 0; i < 4; ++i) {
        int g = (ng * 4 + i) * 8 + h * 4 + ks2;
        short8 Bv = *(const short8*)(w2b + ((size_t)g * 64 + lane) * 8);
        acc2[i] = __builtin_amdgcn_mfma_f32_16x16x32_bf16(A2h, Bv, acc2[i], 0, 0, 0);
        acc2[i] = __builtin_amdgcn_mfma_f32_16x16x32_bf16(A2l, Bv, acc2[i], 0, 0, 0);
      }
    }
  }

  // bias + residual
  float z2[4][4];
#pragma unroll
  for (int i = 0; i < 4; ++i)
#pragma unroll
    for (int r = 0; r < 4; ++r)
      z2[i][r] = acc2[i][r] + b2v[i] + res[i][r];

  __syncthreads();   // all hdn reads done; smem reused for LN2 partials
  // ---- LN2 cross-wave: pbuf[0..127] sums, pbuf[128..255] sumsq ----
  float* pbuf = (float*)smem;
  float ps[4];
#pragma unroll
  for (int r = 0; r < 4; ++r) {
    float s = z2[0][r] + z2[1][r] + z2[2][r] + z2[3][r];
    s += __shfl_xor(s, 1, 64); s += __shfl_xor(s, 2, 64);
    s += __shfl_xor(s, 4, 64); s += __shfl_xor(s, 8, 64);
    ps[r] = s;
  }
  if (m == 0) {
#pragma unroll
    for (int r = 0; r < 4; ++r) pbuf[ng * 64 + pw + quad * 4 + r] = ps[r];
  }
  __syncthreads();
  float mean[4];
#pragma unroll
  for (int r = 0; r < 4; ++r) {
    int px = pw + quad * 4 + r;
    mean[r] = (pbuf[px] + pbuf[64 + px]) * (1.0f / 128.0f);
  }
  float pv[4];
#pragma unroll
  for (int r = 0; r < 4; ++r) {
    float vv = 0.f;
#pragma unroll
    for (int i = 0; i < 4; ++i) { float d = z2[i][r] - mean[r]; vv += d * d; }
    vv += __shfl_xor(vv, 1, 64); vv += __shfl_xor(vv, 2, 64);
    vv += __shfl_xor(vv, 4, 64); vv += __shfl_xor(vv, 8, 64);
    pv[r] = vv;
  }
  if (m == 0) {
#pragma unroll
    for (int r = 0; r < 4; ++r) pbuf[128 + ng * 64 + pw + quad * 4 + r] = pv[r];
  }
  __syncthreads();
  float rstd[4];
#pragma unroll
  for (int r = 0; r < 4; ++r) {
    int px = pw + quad * 4 + r;
    rstd[r] = rsqrtf((pbuf[128 + px] + pbuf[192 + px]) * (1.0f / 128.0f) + 1e-5f);
  }

  __syncthreads();   // pbuf reads done before zo overlay
  // ---- phase 3: zo transpose buffer (128 x 68 floats) ----
  float* zo = (float*)smem;
#pragma unroll
  for (int i = 0; i < 4; ++i)
#pragma unroll
    for (int r = 0; r < 4; ++r) {
      float v = (z2[i][r] - mean[r]) * rstd[r] * g2v[i] + be2v[i];
      zo[((ng * 4 + i) * 16 + m) * 68 + pw + quad * 4 + r] = v;
    }
  __syncthreads();

  // coalesced transposed store: out[b][d][p]
  int bb2 = row0 / P_;
  int p0 = row0 - bb2 * P_;
#pragma unroll
  for (int it = 0; it < 4; ++it) {
    int d = it * 32 + (t >> 4);
    int pq = (t & 15) * 4;
    float4 v4 = *(float4*)&zo[d * 68 + pq];
    *(float4*)(out + (size_t)bb2 * DIM_ * P_ + (size_t)d * P_ + p0 + pq) = v4;
  }
}

extern "C" void kernel_launch(void* const* d_in, const int* in_sizes, int n_in,
                              void* d_out, int out_size, void* d_ws, size_t ws_size,
                              hipStream_t stream) {
  const float* feature = (const float*)d_in[0];
  const float* I_src   = (const float*)d_in[1];
  const float* I_tar   = (const float*)d_in[2];
  const float* E       = (const float*)d_in[3];
  const float* dis     = (const float*)d_in[4];
  const float* nrm     = (const float*)d_in[5];
  const float* conv_w  = (const float*)d_in[6];
  const float* bn_g    = (const float*)d_in[7];
  const float* bn_b    = (const float*)d_in[8];
  const float* bn_m    = (const float*)d_in[9];
  const float* bn_v    = (const float*)d_in[10];
  const float* ln1g    = (const float*)d_in[11];
  const float* ln1b    = (const float*)d_in[12];
  const float* ln2g    = (const float*)d_in[13];
  const float* ln2b    = (const float*)d_in[14];
  const float* w1      = (const float*)d_in[15];
  const float* b1      = (const float*)d_in[16];
  const float* w2      = (const float*)d_in[17];
  const float* b2      = (const float*)d_in[18];
  float* out = (float*)d_out;

  float* wsf = (float*)d_ws;
  float* bns = wsf;                   // 128
  float* bnb = wsf + 128;             // 128
  unsigned short* val_t = (unsigned short*)(wsf + 256);          // B*N*P*DIM bf16 (34.6 MB)
  float* zln = (float*)(val_t + (size_t)B_ * N_ * P_ * DIM_);    // B*P*DIM floats
  Samp*  samp = (Samp*)(zln + (size_t)B_ * P_ * DIM_);           // 12*P structs (32B each)
  short* w1b = (short*)(samp + (size_t)B_ * N_ * P_);            // 32768 shorts each
  short* w2b = w1b + 32768;

  hipLaunchKernelGGL(prep_kernel, dim3(B_ * N_ + 32), dim3(256), 0, stream,
                     I_src, I_tar, E, dis, nrm, bn_g, bn_b, bn_m, bn_v, w1, w2,
                     samp, bns, bnb, w1b, w2b);
  hipLaunchKernelGGL(conv_kernel, dim3(P_ / 64, B_ * N_), dim3(256), 0, stream,
                     feature, conv_w, bns, bnb, val_t);
  hipLaunchKernelGGL(attn_kernel, dim3(B_ * P_ / 4), dim3(256), 0, stream,
                     val_t, samp, ln1g, ln1b, zln);
  hipLaunchKernelGGL(mlp_kernel, dim3(B_ * P_ / 64), dim3(512), 0, stream,
                     zln, w1b, w2b, b1, b2, ln2g, ln2b, out);
}